// Round 14
// baseline (459.415 us; speedup 1.0000x reference)
//
#include <hip/hip_runtime.h>

// ---------------------------------------------------------------------------
// 2-layer GAT (PyG GATConv), MI355X.
// R14: gemm K-loop manually register-double-buffered. R13 evidence: traffic
//      ideal (27MB fetch) but VGPR=92 -> compiler interleaved fragment loads
//      with their MFMAs (serial L2 latency, MfmaUtil 9.5%). Now: two
//      statically-indexed fragment buffers, 64-k loop steps: issue B loads ->
//      compute A -> issue A loads -> compute B. SPLIT=1 buffers raw fp32,
//      converts at consume (wait lands at MFMA). No LDS, no barriers.
//      CSR / prep / aggr unchanged from R13.
// ---------------------------------------------------------------------------

typedef __attribute__((ext_vector_type(8))) short short8;
typedef __attribute__((ext_vector_type(4))) float f32x4;

static __device__ __forceinline__ ushort f2bf(float f) {  // RNE
  uint u = __float_as_uint(f);
  return (ushort)((u + 0x7FFFu + ((u >> 16) & 1u)) >> 16);
}
static __device__ __forceinline__ float bf2f(ushort s) {
  return __uint_as_float(((uint)s) << 16);
}
static __device__ __forceinline__ void split8(const float4& a, const float4& b,
                                              short8& fh, short8& fl) {
  ushort h0 = f2bf(a.x), h1 = f2bf(a.y), h2 = f2bf(a.z), h3 = f2bf(a.w);
  ushort h4 = f2bf(b.x), h5 = f2bf(b.y), h6 = f2bf(b.z), h7 = f2bf(b.w);
  fh = short8{(short)h0, (short)h1, (short)h2, (short)h3,
              (short)h4, (short)h5, (short)h6, (short)h7};
  fl = short8{(short)f2bf(a.x - bf2f(h0)), (short)f2bf(a.y - bf2f(h1)),
              (short)f2bf(a.z - bf2f(h2)), (short)f2bf(a.w - bf2f(h3)),
              (short)f2bf(b.x - bf2f(h4)), (short)f2bf(b.y - bf2f(h5)),
              (short)f2bf(b.z - bf2f(h6)), (short)f2bf(b.w - bf2f(h7))};
}

// ----------------------------- CSR build -----------------------------------
__global__ __launch_bounds__(256)
void k_hist(const int* __restrict__ dstv, int* __restrict__ cnt, int E) {
  int i = blockIdx.x * 256 + threadIdx.x;
  if (i < E) atomicAdd(&cnt[dstv[i]], 1);
}

// Single-pass exclusive scan with decoupled lookback (grid <= 256 blocks).
__global__ __launch_bounds__(256)
void k_scan(const int* __restrict__ cnt, int* __restrict__ rowptr,
            int* __restrict__ cursor, int* __restrict__ bsum,
            int* __restrict__ bflag, int N, int E) {
  __shared__ int sm[256];
  __shared__ int s_prev;
  const int b = blockIdx.x, tid = threadIdx.x;
  const int gid = b * 256 + tid;
  int v = (gid < N) ? cnt[gid] : 0;
  sm[tid] = v;
  __syncthreads();
  for (int off = 1; off < 256; off <<= 1) {
    int t = (tid >= off) ? sm[tid - off] : 0;
    __syncthreads();
    sm[tid] += t;
    __syncthreads();
  }
  if (tid == 255) {
    atomicExch(&bsum[b], sm[255]);
    __threadfence();
    atomicExch(&bflag[b], 1);
  }
  if (tid == 0) s_prev = 0;
  __syncthreads();
  if (tid < b) {
    while (atomicAdd(&bflag[tid], 0) == 0) {}
    atomicAdd(&s_prev, atomicAdd(&bsum[tid], 0));
  }
  __syncthreads();
  if (gid < N) {
    int rp = s_prev + sm[tid] - v;
    rowptr[gid] = rp;
    cursor[gid] = rp;
  }
  if (gid == 0) rowptr[N] = E;
}

__global__ __launch_bounds__(256)
void k_scatter(const int* __restrict__ srcv, const int* __restrict__ dstv,
               int* __restrict__ cursor, int* __restrict__ col, int E) {
  int i = blockIdx.x * 256 + threadIdx.x;
  if (i < E) {
    int p = atomicAdd(&cursor[dstv[i]], 1);
    col[p] = srcv[i];
  }
}

// --------------------- weight prep (both layers, one launch) ---------------
__global__ __launch_bounds__(256)
void k_prep_w(const float* __restrict__ W1, const float* __restrict__ W2,
              ushort* __restrict__ w1th, ushort* __restrict__ w1tl,
              ushort* __restrict__ w2th, ushort* __restrict__ w2tl) {
  int bid = blockIdx.x;
  if (bid < 128) {  // W1 [128][256] -> [256][128] split
    int gid = bid * 256 + threadIdx.x;
    int c = gid & 255, k = gid >> 8;
    float w = W1[(size_t)k * 256 + c];
    ushort h = f2bf(w);
    w1th[(size_t)c * 128 + k] = h;
    w1tl[(size_t)c * 128 + k] = f2bf(w - bf2f(h));
  } else {          // W2 [256][256] -> [256][256] split
    int gid = (bid - 128) * 256 + threadIdx.x;
    int c = gid & 255, k = gid >> 8;
    float w = W2[(size_t)k * 256 + c];
    ushort h = f2bf(w);
    w2th[(size_t)c * 256 + k] = h;
    w2tl[(size_t)c * 256 + k] = f2bf(w - bf2f(h));
  }
}

// ----------------------------- MFMA GEMM -----------------------------------
// C[N,256] = (Ah+Al)[N,K] @ (Bh+Bl)[K,256], Bt stored [256][K].
// Barrier-free, no LDS; manual register double-buffer over 64-k steps
// (K is always a multiple of 64). Static buffer indices -> no scratch.
// XCD-aligned 1-D swizzle (R11): col-halves of a row block differ by 8
// block ids -> same XCD -> shared A tile hits local L2.
template <int SPLIT>
__global__ __launch_bounds__(256)
void k_gemm_mfma(const void* __restrict__ Aany, const ushort* __restrict__ Al_,
                 const ushort* __restrict__ Bth, const ushort* __restrict__ Btl,
                 ushort* __restrict__ hout, int Nrows, int K,
                 const float* __restrict__ att_s, const float* __restrict__ att_d,
                 float* __restrict__ a_s, float* __restrict__ a_d) {
  const int nrb = (Nrows + 127) >> 7;
  const int bid = blockIdx.x;
  const int rb = (bid >> 4) * 8 + (bid & 7);
  const int ch = (bid >> 3) & 1;
  if (rb >= nrb) return;
  const int row0 = rb * 128;
  const int col0 = ch * 128;

  const int lane = threadIdx.x & 63;
  const int w = threadIdx.x >> 6;
  const int wr = (w >> 1) * 64;
  const int wc = (w & 1) * 64;
  const int fr = lane & 15;
  const int fq = lane >> 4;

  const float*  Af = (const float*)Aany;    // SPLIT=1
  const ushort* Ah = (const ushort*)Aany;   // SPLIT=0

  int grr[4];
#pragma unroll
  for (int r = 0; r < 4; r++) {
    int g = row0 + wr + r * 16 + fr;
    grr[r] = (g < Nrows) ? g : (Nrows - 1);
  }
  const ushort* bb_h = Bth + (size_t)(col0 + wc + fr) * K + fq * 8;
  const ushort* bb_l = Btl + (size_t)(col0 + wc + fr) * K + fq * 8;

  f32x4 acc[4][4] = {};

  // two fragment buffer sets (statically indexed)
  short8 fA_h[2][4], fA_l[2][4], fB_h[2][4], fB_l[2][4];
  float4 rawA0[2][4], rawA1[2][4];  // SPLIT=1 raw fp32

#define LOADSET(B, KOFF)                                                     \
  {                                                                          \
    _Pragma("unroll") for (int r = 0; r < 4; r++) {                          \
      if (SPLIT) {                                                           \
        const float* ap = Af + (size_t)grr[r] * K + (KOFF) + fq * 8;         \
        rawA0[B][r] = *(const float4*)(ap);                                  \
        rawA1[B][r] = *(const float4*)(ap + 4);                              \
      } else {                                                               \
        fA_h[B][r] = *(const short8*)(Ah + (size_t)grr[r] * K + (KOFF) + fq * 8); \
        fA_l[B][r] = *(const short8*)(Al_ + (size_t)grr[r] * K + (KOFF) + fq * 8); \
      }                                                                      \
    }                                                                        \
    _Pragma("unroll") for (int c = 0; c < 4; c++) {                          \
      fB_h[B][c] = *(const short8*)(bb_h + (size_t)c * 16 * K + (KOFF));     \
      fB_l[B][c] = *(const short8*)(bb_l + (size_t)c * 16 * K + (KOFF));     \
    }                                                                        \
  }

#define COMPUTESET(B)                                                        \
  {                                                                          \
    short8 ah[4], al[4];                                                     \
    _Pragma("unroll") for (int r = 0; r < 4; r++) {                          \
      if (SPLIT) split8(rawA0[B][r], rawA1[B][r], ah[r], al[r]);             \
      else { ah[r] = fA_h[B][r]; al[r] = fA_l[B][r]; }                       \
    }                                                                        \
    _Pragma("unroll") for (int r = 0; r < 4; r++)                            \
      _Pragma("unroll") for (int c = 0; c < 4; c++) {                        \
        acc[r][c] = __builtin_amdgcn_mfma_f32_16x16x32_bf16(ah[r], fB_h[B][c], acc[r][c], 0, 0, 0); \
        acc[r][c] = __builtin_amdgcn_mfma_f32_16x16x32_bf16(al[r], fB_h[B][c], acc[r][c], 0, 0, 0); \
        acc[r][c] = __builtin_amdgcn_mfma_f32_16x16x32_bf16(ah[r], fB_l[B][c], acc[r][c], 0, 0, 0); \
      }                                                                      \
  }

  LOADSET(0, 0)
  for (int k0 = 0; k0 < K; k0 += 64) {
    if (k0 + 32 < K) LOADSET(1, k0 + 32)
    COMPUTESET(0)
    if (k0 + 64 < K) LOADSET(0, k0 + 64)
    COMPUTESET(1)
  }
#undef LOADSET
#undef COMPUTESET

  // ---- C write (bf16, direct — L2 absorbs the 2B scatter, R10 evidence)
#pragma unroll
  for (int r = 0; r < 4; r++)
#pragma unroll
    for (int c = 0; c < 4; c++) {
      int colg = col0 + wc + c * 16 + fr;
#pragma unroll
      for (int reg = 0; reg < 4; reg++) {
        int gr = row0 + wr + r * 16 + fq * 4 + reg;
        if (gr < Nrows) hout[(size_t)gr * 256 + colg] = f2bf(acc[r][c][reg]);
      }
    }

  // ---- attention scores: wave's 64 cols = one head (wc 64-aligned)
  const int head = (col0 + wc) >> 6;
  float asv[4], adv[4];
#pragma unroll
  for (int c = 0; c < 4; c++) {
    asv[c] = att_s[col0 + wc + c * 16 + fr];
    adv[c] = att_d[col0 + wc + c * 16 + fr];
  }
#pragma unroll
  for (int r = 0; r < 4; r++)
#pragma unroll
    for (int reg = 0; reg < 4; reg++) {
      float ps = 0.f, pd = 0.f;
#pragma unroll
      for (int c = 0; c < 4; c++) {
        ps += acc[r][c][reg] * asv[c];
        pd += acc[r][c][reg] * adv[c];
      }
      ps += __shfl_xor(ps, 1); pd += __shfl_xor(pd, 1);
      ps += __shfl_xor(ps, 2); pd += __shfl_xor(pd, 2);
      ps += __shfl_xor(ps, 4); pd += __shfl_xor(pd, 4);
      ps += __shfl_xor(ps, 8); pd += __shfl_xor(pd, 8);
      if (fr == 0) {
        int gr = row0 + wr + r * 16 + fq * 4 + reg;
        if (gr < Nrows) {
          a_s[(size_t)gr * 4 + head] = ps;
          a_d[(size_t)gr * 4 + head] = pd;
        }
      }
    }
}

// ----------------------------- aggregation ---------------------------------
// ONE wave per node; lane owns channels [4*lane, 4*lane+3] (ushort4 gather),
// head = lane>>4. Chunk of 64 edges: lane gathers a_s[col] float4, computes
// all-head weights inline, stages (src, w[4]) in LDS. Denominator free.
// LAYER 1: relu(acc/den + bias) -> split bf16 (out_h, out_l).
// LAYER 2: fused finale — head-mean + bias + relu + softmax(64) -> outp.
template <int LAYER>
__global__ __launch_bounds__(256)
void k_aggr(const ushort* __restrict__ hsrc, const int* __restrict__ rowptr,
            const int* __restrict__ col, const float* __restrict__ a_s,
            const float* __restrict__ a_d, const float* __restrict__ bias,
            ushort* __restrict__ out_h, ushort* __restrict__ out_l,
            float* __restrict__ outp, int N) {
  __shared__ int   s_sh[4][64];
  __shared__ float w_sh[4][256];
  const int wv = threadIdx.x >> 6;
  const int lane = threadIdx.x & 63;
  const int node = blockIdx.x * 4 + wv;
  if (node >= N) return;
  const int hd = lane >> 4;
  const int beg = rowptr[node], end = rowptr[node + 1];
  const float4 adst = *(const float4*)(a_d + (size_t)node * 4);

  float4 acc = make_float4(0.f, 0.f, 0.f, 0.f);
  float wsum = 0.f;
  const char* hbase = (const char*)(hsrc + lane * 4);

  for (int c0 = beg; c0 < end; c0 += 64) {
    int nc = min(64, end - c0);
    int s = 0;
    float4 w4 = make_float4(0.f, 0.f, 0.f, 0.f);
    if (lane < nc) {
      s = col[c0 + lane];
      float4 a = *(const float4*)(a_s + (size_t)s * 4);
      float e0 = a.x + adst.x; e0 = e0 > 0.f ? e0 : 0.2f * e0;
      float e1 = a.y + adst.y; e1 = e1 > 0.f ? e1 : 0.2f * e1;
      float e2 = a.z + adst.z; e2 = e2 > 0.f ? e2 : 0.2f * e2;
      float e3 = a.w + adst.w; e3 = e3 > 0.f ? e3 : 0.2f * e3;
      w4 = make_float4(__expf(e0), __expf(e1), __expf(e2), __expf(e3));
    }
    s_sh[wv][lane] = s;
    *(float4*)(&w_sh[wv][lane * 4]) = w4;
    asm volatile("s_waitcnt lgkmcnt(0)" ::: "memory");

    const float* wrow = &w_sh[wv][hd];
    const int*   srow = &s_sh[wv][0];
    int j = 0;
    for (; j + 4 <= nc; j += 4) {
      int sj0 = srow[j], sj1 = srow[j + 1], sj2 = srow[j + 2], sj3 = srow[j + 3];
      float w0 = wrow[4 * j],      w1 = wrow[4 * j + 4];
      float w2 = wrow[4 * j + 8],  w3 = wrow[4 * j + 12];
      ushort4 u0 = *(const ushort4*)(hbase + ((size_t)((uint)sj0 << 9)));
      ushort4 u1 = *(const ushort4*)(hbase + ((size_t)((uint)sj1 << 9)));
      ushort4 u2 = *(const ushort4*)(hbase + ((size_t)((uint)sj2 << 9)));
      ushort4 u3 = *(const ushort4*)(hbase + ((size_t)((uint)sj3 << 9)));
      wsum += w0 + w1 + w2 + w3;
      acc.x += w0 * bf2f(u0.x); acc.y += w0 * bf2f(u0.y);
      acc.z += w0 * bf2f(u0.z); acc.w += w0 * bf2f(u0.w);
      acc.x += w1 * bf2f(u1.x); acc.y += w1 * bf2f(u1.y);
      acc.z += w1 * bf2f(u1.z); acc.w += w1 * bf2f(u1.w);
      acc.x += w2 * bf2f(u2.x); acc.y += w2 * bf2f(u2.y);
      acc.z += w2 * bf2f(u2.z); acc.w += w2 * bf2f(u2.w);
      acc.x += w3 * bf2f(u3.x); acc.y += w3 * bf2f(u3.y);
      acc.z += w3 * bf2f(u3.z); acc.w += w3 * bf2f(u3.w);
    }
    for (; j < nc; j++) {
      int sj = srow[j];
      float ww = wrow[4 * j];
      ushort4 u = *(const ushort4*)(hbase + ((size_t)((uint)sj << 9)));
      wsum += ww;
      acc.x += ww * bf2f(u.x); acc.y += ww * bf2f(u.y);
      acc.z += ww * bf2f(u.z); acc.w += ww * bf2f(u.w);
    }
  }

  float inv = 1.0f / wsum;  // deg>=1 via self-loop
  float4 v = make_float4(acc.x * inv, acc.y * inv, acc.z * inv, acc.w * inv);

  if (LAYER == 1) {
    const float4 bv = *(const float4*)(bias + lane * 4);
    v.x = fmaxf(v.x + bv.x, 0.f);
    v.y = fmaxf(v.y + bv.y, 0.f);
    v.z = fmaxf(v.z + bv.z, 0.f);
    v.w = fmaxf(v.w + bv.w, 0.f);
    ushort4 h, l;
    h.x = f2bf(v.x); l.x = f2bf(v.x - bf2f(h.x));
    h.y = f2bf(v.y); l.y = f2bf(v.y - bf2f(h.y));
    h.z = f2bf(v.z); l.z = f2bf(v.z - bf2f(h.z));
    h.w = f2bf(v.w); l.w = f2bf(v.w - bf2f(h.w));
    const size_t o = (size_t)node * 256 + lane * 4;
    *(ushort4*)(out_h + o) = h;
    *(ushort4*)(out_l + o) = l;
  } else {
    // fused finale: head-mean + bias + relu + softmax(64)
    v.x += __shfl_xor(v.x, 16); v.y += __shfl_xor(v.y, 16);
    v.z += __shfl_xor(v.z, 16); v.w += __shfl_xor(v.w, 16);
    v.x += __shfl_xor(v.x, 32); v.y += __shfl_xor(v.y, 32);
    v.z += __shfl_xor(v.z, 32); v.w += __shfl_xor(v.w, 32);
    const int c4 = (lane & 15) * 4;
    const float4 bv = *(const float4*)(bias + c4);
    v.x = fmaxf(v.x * 0.25f + bv.x, 0.f);
    v.y = fmaxf(v.y * 0.25f + bv.y, 0.f);
    v.z = fmaxf(v.z * 0.25f + bv.z, 0.f);
    v.w = fmaxf(v.w * 0.25f + bv.w, 0.f);
    float mx = fmaxf(fmaxf(v.x, v.y), fmaxf(v.z, v.w));
    for (int off = 8; off >= 1; off >>= 1) mx = fmaxf(mx, __shfl_xor(mx, off));
    v.x = __expf(v.x - mx); v.y = __expf(v.y - mx);
    v.z = __expf(v.z - mx); v.w = __expf(v.w - mx);
    float sum = v.x + v.y + v.z + v.w;
    for (int off = 8; off >= 1; off >>= 1) sum += __shfl_xor(sum, off);
    float is = 1.0f / sum;
    v.x *= is; v.y *= is; v.z *= is; v.w *= is;
    if (lane < 16) *(float4*)(outp + (size_t)node * 64 + c4) = v;
  }
}

// ---------------------------------------------------------------------------

extern "C" void kernel_launch(void* const* d_in, const int* in_sizes, int n_in,
                              void* d_out, int out_size, void* d_ws, size_t ws_size,
                              hipStream_t stream) {
  const float* x   = (const float*)d_in[0];
  const int*   ei  = (const int*)d_in[1];
  const float* W1  = (const float*)d_in[2];
  const float* as1 = (const float*)d_in[3];
  const float* ad1 = (const float*)d_in[4];
  const float* b1  = (const float*)d_in[5];
  const float* W2  = (const float*)d_in[6];
  const float* as2 = (const float*)d_in[7];
  const float* ad2 = (const float*)d_in[8];
  const float* b2  = (const float*)d_in[9];
  float* out = (float*)d_out;

  const int N = in_sizes[0] / 128;
  const int E = in_sizes[1] / 2;
  const int* srcv = ei;
  const int* dstv = ei + E;

  // ---- workspace layout
  ushort* h1   = (ushort*)d_ws;                   // [N,256] bf16 (also h2)
  ushort* hb_h = h1 + (size_t)N * 256;            // [N,256] bf16
  ushort* hb_l = hb_h + (size_t)N * 256;          // [N,256] bf16
  ushort* w1th = hb_l + (size_t)N * 256;          // [256][128] x2
  ushort* w1tl = w1th + 256 * 128;
  ushort* w2th = w1tl + 256 * 128;                // [256][256] x2
  ushort* w2tl = w2th + 256 * 256;
  float*  zbuf = (float*)(w2tl + 256 * 256);      // a_s1,a_d1,a_s2,a_d2 [16N]
  float* a_s1 = zbuf;
  float* a_d1 = a_s1 + (size_t)N * 4;
  float* a_s2 = a_d1 + (size_t)N * 4;
  float* a_d2 = a_s2 + (size_t)N * 4;
  int* rowptr = (int*)(zbuf + (size_t)N * 16);    // [N+1] (+pad)
  int* cnt    = rowptr + (N + 4);                 // [N]      (memset region)
  int* bflag  = cnt + N;                          // [256]    (memset region)
  int* bsum   = bflag + 256;                      // [256]
  int* cursor = bsum + 256;                       // [N]
  int* colx   = cursor + N;                       // [E]

  const int nb = (N + 255) / 256;  // <=256 required by k_scan lookback
  const int eb = (E + 255) / 256;

  hipMemsetAsync(cnt, 0, ((size_t)N + 256) * 4, stream);  // cnt + bflag
  k_hist<<<eb, 256, 0, stream>>>(dstv, cnt, E);
  k_scan<<<nb, 256, 0, stream>>>(cnt, rowptr, cursor, bsum, bflag, N, E);
  k_scatter<<<eb, 256, 0, stream>>>(srcv, dstv, cursor, colx, E);
  k_prep_w<<<384, 256, 0, stream>>>(W1, W2, w1th, w1tl, w2th, w2tl);

  // XCD-aligned swizzled 1-D grid: 16 blocks per group of 8 row blocks
  const int nrb = (N + 127) / 128;
  const int gemm_blocks = ((nrb + 7) / 8) * 16;
  const int wb = (N + 3) / 4;  // one wave per node

  k_gemm_mfma<1><<<gemm_blocks, 256, 0, stream>>>(x, nullptr, w1th, w1tl,
                                                  h1, N, 128,
                                                  as1, ad1, a_s1, a_d1);
  k_aggr<1><<<wb, 256, 0, stream>>>(h1, rowptr, colx, a_s1, a_d1, b1,
                                    hb_h, hb_l, nullptr, N);
  k_gemm_mfma<0><<<gemm_blocks, 256, 0, stream>>>(hb_h, hb_l, w2th, w2tl,
                                                  h1, N, 256,
                                                  as2, ad2, a_s2, a_d2);
  k_aggr<2><<<wb, 256, 0, stream>>>(h1, rowptr, colx, a_s2, a_d2, b2,
                                    nullptr, nullptr, out, N);
}

// Round 15
// 438.889 us; speedup vs baseline: 1.0468x; 1.0468x over previous
//
#include <hip/hip_runtime.h>

// ---------------------------------------------------------------------------
// 2-layer GAT (PyG GATConv), MI355X.
// R15: (1) gemm reverted to R12 (LDS-A staging + direct-B; best measured —
//      R13 global-direct and R14 reg-dbuf both lost to occupancy/latency).
//      (2) CSR+prep fused into ONE cooperative kernel with hand-rolled
//      atomic barriers (~150us was sitting in 5 small dispatches + gaps).
//      All cross-block-within-kernel data goes through ATOMICS (exch/add/
//      read) -> no L2 fence semantics needed (unlike R3's grid.sync 224us).
//      9 -> 6 dispatches. aggr unchanged.
// ---------------------------------------------------------------------------

typedef __attribute__((ext_vector_type(8))) short short8;
typedef __attribute__((ext_vector_type(4))) float f32x4;

static __device__ __forceinline__ ushort f2bf(float f) {  // RNE
  uint u = __float_as_uint(f);
  return (ushort)((u + 0x7FFFu + ((u >> 16) & 1u)) >> 16);
}
static __device__ __forceinline__ float bf2f(ushort s) {
  return __uint_as_float(((uint)s) << 16);
}
static __device__ __forceinline__ void split8(const float4& a, const float4& b,
                                              uint4& hh, uint4& ll) {
  ushort h0 = f2bf(a.x), h1 = f2bf(a.y), h2 = f2bf(a.z), h3 = f2bf(a.w);
  ushort h4 = f2bf(b.x), h5 = f2bf(b.y), h6 = f2bf(b.z), h7 = f2bf(b.w);
  hh.x = (uint)h0 | ((uint)h1 << 16); hh.y = (uint)h2 | ((uint)h3 << 16);
  hh.z = (uint)h4 | ((uint)h5 << 16); hh.w = (uint)h6 | ((uint)h7 << 16);
  ll.x = (uint)f2bf(a.x - bf2f(h0)) | ((uint)f2bf(a.y - bf2f(h1)) << 16);
  ll.y = (uint)f2bf(a.z - bf2f(h2)) | ((uint)f2bf(a.w - bf2f(h3)) << 16);
  ll.z = (uint)f2bf(b.x - bf2f(h4)) | ((uint)f2bf(b.y - bf2f(h5)) << 16);
  ll.w = (uint)f2bf(b.z - bf2f(h6)) | ((uint)f2bf(b.w - bf2f(h7)) << 16);
}

// --------------------- fused CSR + weight prep (cooperative) ---------------
// Hand-rolled grid barrier: pure atomic counter, no data fences needed
// because ALL cross-block data inside this kernel moves via atomics
// (coherent point). bar[4] zeroed by host-side memset each launch.
static __device__ __forceinline__ void gbar(int* bar, int slot, int G) {
  __syncthreads();
  if (threadIdx.x == 0) {
    atomicAdd(&bar[slot], 1);
    while (atomicAdd(&bar[slot], 0) < G) __builtin_amdgcn_s_sleep(2);
  }
  __syncthreads();
}

__global__ __launch_bounds__(256)
void k_csr_all(const int* __restrict__ srcv, const int* __restrict__ dstv,
               const float* __restrict__ W1, const float* __restrict__ W2,
               ushort* __restrict__ w1th, ushort* __restrict__ w1tl,
               ushort* __restrict__ w2th, ushort* __restrict__ w2tl,
               int* __restrict__ cnt, int* __restrict__ rowptr,
               int* __restrict__ cursor, int* __restrict__ col,
               int* __restrict__ bsum, int* __restrict__ bar,
               int N, int E) {
  const int G = gridDim.x;
  const int b = blockIdx.x, tid = threadIdx.x;
  const int gid0 = b * 256 + tid;
  const int nthr = G * 256;
  __shared__ int sm[256];

  // ---- phase 0: zero cnt (atomic -> no dirty lines) + weight prep
  for (int i = gid0; i < N; i += nthr) atomicExch(&cnt[i], 0);
  for (int i = gid0; i < 128 * 256; i += nthr) {  // W1 -> [256][128] split
    int c = i & 255, k = i >> 8;
    float w = W1[(size_t)k * 256 + c];
    ushort h = f2bf(w);
    w1th[(size_t)c * 128 + k] = h;
    w1tl[(size_t)c * 128 + k] = f2bf(w - bf2f(h));
  }
  for (int i = gid0; i < 256 * 256; i += nthr) {  // W2 -> [256][256] split
    int c = i & 255, k = i >> 8;
    float w = W2[(size_t)k * 256 + c];
    ushort h = f2bf(w);
    w2th[(size_t)c * 256 + k] = h;
    w2tl[(size_t)c * 256 + k] = f2bf(w - bf2f(h));
  }
  gbar(bar, 0, G);

  // ---- phase 1: histogram of dst
  for (int i = gid0; i < E; i += nthr) atomicAdd(&cnt[dstv[i]], 1);
  gbar(bar, 1, G);

  // ---- phase 2a: per-block local exclusive scan of its 256-node chunk
  {
    int v = (gid0 < N) ? atomicAdd(&cnt[gid0], 0) : 0;
    sm[tid] = v;
    __syncthreads();
    for (int off = 1; off < 256; off <<= 1) {
      int t = (tid >= off) ? sm[tid - off] : 0;
      __syncthreads();
      sm[tid] += t;
      __syncthreads();
    }
    if (gid0 < N) rowptr[gid0] = sm[tid] - v;  // local exclusive
    if (tid == 255) atomicExch(&bsum[b], sm[255]);
  }
  gbar(bar, 2, G);

  // ---- phase 2b: add block offsets (each block scans the 196 totals)
  {
    int v = (tid < G) ? atomicAdd(&bsum[tid], 0) : 0;
    sm[tid] = v;
    __syncthreads();
    for (int off = 1; off < 256; off <<= 1) {
      int t = (tid >= off) ? sm[tid - off] : 0;
      __syncthreads();
      sm[tid] += t;
      __syncthreads();
    }
    int boff = (b == 0) ? 0 : sm[b - 1];  // exclusive prefix of totals
    __syncthreads();
    if (gid0 < N) {
      int rp = rowptr[gid0] + boff;
      rowptr[gid0] = rp;
      atomicExch(&cursor[gid0], rp);  // coherent write for phase-3 atomics
    }
    if (gid0 == 0) rowptr[N] = E;
  }
  gbar(bar, 3, G);

  // ---- phase 3: scatter src into CSR col
  for (int i = gid0; i < E; i += nthr) {
    int p = atomicAdd(&cursor[dstv[i]], 1);
    col[p] = srcv[i];  // normal store: read only by later dispatches
  }
}

// ----------------------------- MFMA GEMM (R12 version) ---------------------
// C[N,256] = (Ah+Al)[N,K] @ (Bh+Bl)[K,256], Bt stored [256][K].
// SPLIT=1: A is fp32 (x), split to bf16 h/l inline during LDS staging.
// SPLIT=0: A pre-split bf16 (hb_h, hb_l).
// B fragments loaded per k-tile directly from global (panel L1/L2-hot).
// LDS holds A only. XCD-aligned 1-D swizzle: col-halves of a row block
// differ by 8 block ids -> same XCD -> A's 2nd read hits local L2.
template <int SPLIT>
__global__ __launch_bounds__(256)
void k_gemm_mfma(const void* __restrict__ Aany, const ushort* __restrict__ Al_,
                 const ushort* __restrict__ Bth, const ushort* __restrict__ Btl,
                 ushort* __restrict__ hout, int Nrows, int K,
                 const float* __restrict__ att_s, const float* __restrict__ att_d,
                 float* __restrict__ a_s, float* __restrict__ a_d) {
  __shared__ ushort As_h[128][40];
  __shared__ ushort As_l[128][40];

  const int nrb = (Nrows + 127) >> 7;
  const int bid = blockIdx.x;
  const int rb = (bid >> 4) * 8 + (bid & 7);
  const int ch = (bid >> 3) & 1;
  if (rb >= nrb) return;
  const int row0 = rb * 128;
  const int col0 = ch * 128;

  const int t = threadIdx.x;
  const int lane = t & 63;
  const int w = t >> 6;
  const int wr = (w >> 1) * 64;
  const int wc = (w & 1) * 64;
  const int lrow = t >> 2;       // 0..63 staging row index
  const int kc = (t & 3) * 8;    // k-chunk within BK=32

  const float*  Af = (const float*)Aany;    // SPLIT=1
  const ushort* Ah = (const ushort*)Aany;   // SPLIT=0

  f32x4 acc[4][4] = {};

  float4 pf[2][2];
  uint4 pa_h[2], pa_l[2];
  const uint4 z4 = make_uint4(0, 0, 0, 0);
#pragma unroll
  for (int p = 0; p < 2; p++) {
    int gr = row0 + p * 64 + lrow;
    if (SPLIT) {
      if (gr < Nrows) {
        const float* ap = Af + (size_t)gr * K + kc;
        pf[p][0] = *(const float4*)(ap);
        pf[p][1] = *(const float4*)(ap + 4);
      } else {
        pf[p][0] = make_float4(0.f, 0.f, 0.f, 0.f);
        pf[p][1] = pf[p][0];
      }
    } else {
      if (gr < Nrows) {
        pa_h[p] = *(const uint4*)(Ah + (size_t)gr * K + kc);
        pa_l[p] = *(const uint4*)(Al_ + (size_t)gr * K + kc);
      } else { pa_h[p] = z4; pa_l[p] = z4; }
    }
  }

  const int fr = lane & 15;
  const int fq = lane >> 4;
  const ushort* bb_h = Bth + (size_t)(col0 + wc + fr) * K + fq * 8;
  const ushort* bb_l = Btl + (size_t)(col0 + wc + fr) * K + fq * 8;

  for (int k0 = 0; k0 < K; k0 += 32) {
#pragma unroll
    for (int p = 0; p < 2; p++) {
      uint4 hh, ll;
      if (SPLIT) split8(pf[p][0], pf[p][1], hh, ll);
      else { hh = pa_h[p]; ll = pa_l[p]; }
      *(uint4*)(&As_h[p * 64 + lrow][kc]) = hh;
      *(uint4*)(&As_l[p * 64 + lrow][kc]) = ll;
    }
    __syncthreads();

    if (k0 + 32 < K) {
#pragma unroll
      for (int p = 0; p < 2; p++) {
        int gr = row0 + p * 64 + lrow;
        if (SPLIT) {
          if (gr < Nrows) {
            const float* ap = Af + (size_t)gr * K + k0 + 32 + kc;
            pf[p][0] = *(const float4*)(ap);
            pf[p][1] = *(const float4*)(ap + 4);
          } else {
            pf[p][0] = make_float4(0.f, 0.f, 0.f, 0.f);
            pf[p][1] = pf[p][0];
          }
        } else {
          if (gr < Nrows) {
            pa_h[p] = *(const uint4*)(Ah + (size_t)gr * K + k0 + 32 + kc);
            pa_l[p] = *(const uint4*)(Al_ + (size_t)gr * K + k0 + 32 + kc);
          } else { pa_h[p] = z4; pa_l[p] = z4; }
        }
      }
    }

    short8 fb_h[4], fb_l[4];
#pragma unroll
    for (int c = 0; c < 4; c++) {
      fb_h[c] = *(const short8*)(bb_h + (size_t)c * 16 * K + k0);
      fb_l[c] = *(const short8*)(bb_l + (size_t)c * 16 * K + k0);
    }
    short8 fa_h[4], fa_l[4];
#pragma unroll
    for (int r = 0; r < 4; r++) {
      fa_h[r] = *(const short8*)(&As_h[wr + r * 16 + fr][fq * 8]);
      fa_l[r] = *(const short8*)(&As_l[wr + r * 16 + fr][fq * 8]);
    }
#pragma unroll
    for (int r = 0; r < 4; r++)
#pragma unroll
      for (int c = 0; c < 4; c++) {
        acc[r][c] = __builtin_amdgcn_mfma_f32_16x16x32_bf16(fa_h[r], fb_h[c], acc[r][c], 0, 0, 0);
        acc[r][c] = __builtin_amdgcn_mfma_f32_16x16x32_bf16(fa_l[r], fb_h[c], acc[r][c], 0, 0, 0);
        acc[r][c] = __builtin_amdgcn_mfma_f32_16x16x32_bf16(fa_h[r], fb_l[c], acc[r][c], 0, 0, 0);
      }
    __syncthreads();
  }

  // ---- C write (bf16, direct — L2 absorbs the 2B scatter, R10 evidence)
#pragma unroll
  for (int r = 0; r < 4; r++)
#pragma unroll
    for (int c = 0; c < 4; c++) {
      int colg = col0 + wc + c * 16 + fr;
#pragma unroll
      for (int reg = 0; reg < 4; reg++) {
        int gr = row0 + wr + r * 16 + fq * 4 + reg;
        if (gr < Nrows) hout[(size_t)gr * 256 + colg] = f2bf(acc[r][c][reg]);
      }
    }

  // ---- attention scores: wave's 64 cols = one head (wc 64-aligned)
  const int head = (col0 + wc) >> 6;
  float asv[4], adv[4];
#pragma unroll
  for (int c = 0; c < 4; c++) {
    asv[c] = att_s[col0 + wc + c * 16 + fr];
    adv[c] = att_d[col0 + wc + c * 16 + fr];
  }
#pragma unroll
  for (int r = 0; r < 4; r++)
#pragma unroll
    for (int reg = 0; reg < 4; reg++) {
      float ps = 0.f, pd = 0.f;
#pragma unroll
      for (int c = 0; c < 4; c++) {
        ps += acc[r][c][reg] * asv[c];
        pd += acc[r][c][reg] * adv[c];
      }
      ps += __shfl_xor(ps, 1); pd += __shfl_xor(pd, 1);
      ps += __shfl_xor(ps, 2); pd += __shfl_xor(pd, 2);
      ps += __shfl_xor(ps, 4); pd += __shfl_xor(pd, 4);
      ps += __shfl_xor(ps, 8); pd += __shfl_xor(pd, 8);
      if (fr == 0) {
        int gr = row0 + wr + r * 16 + fq * 4 + reg;
        if (gr < Nrows) {
          a_s[(size_t)gr * 4 + head] = ps;
          a_d[(size_t)gr * 4 + head] = pd;
        }
      }
    }
}

// ----------------------------- aggregation ---------------------------------
// ONE wave per node; lane owns channels [4*lane, 4*lane+3] (ushort4 gather),
// head = lane>>4. Chunk of 64 edges: lane gathers a_s[col] float4, computes
// all-head weights inline, stages (src, w[4]) in LDS. Denominator free.
// LAYER 1: relu(acc/den + bias) -> split bf16 (out_h, out_l).
// LAYER 2: fused finale — head-mean + bias + relu + softmax(64) -> outp.
template <int LAYER>
__global__ __launch_bounds__(256)
void k_aggr(const ushort* __restrict__ hsrc, const int* __restrict__ rowptr,
            const int* __restrict__ col, const float* __restrict__ a_s,
            const float* __restrict__ a_d, const float* __restrict__ bias,
            ushort* __restrict__ out_h, ushort* __restrict__ out_l,
            float* __restrict__ outp, int N) {
  __shared__ int   s_sh[4][64];
  __shared__ float w_sh[4][256];
  const int wv = threadIdx.x >> 6;
  const int lane = threadIdx.x & 63;
  const int node = blockIdx.x * 4 + wv;
  if (node >= N) return;
  const int hd = lane >> 4;
  const int beg = rowptr[node], end = rowptr[node + 1];
  const float4 adst = *(const float4*)(a_d + (size_t)node * 4);

  float4 acc = make_float4(0.f, 0.f, 0.f, 0.f);
  float wsum = 0.f;
  const char* hbase = (const char*)(hsrc + lane * 4);

  for (int c0 = beg; c0 < end; c0 += 64) {
    int nc = min(64, end - c0);
    int s = 0;
    float4 w4 = make_float4(0.f, 0.f, 0.f, 0.f);
    if (lane < nc) {
      s = col[c0 + lane];
      float4 a = *(const float4*)(a_s + (size_t)s * 4);
      float e0 = a.x + adst.x; e0 = e0 > 0.f ? e0 : 0.2f * e0;
      float e1 = a.y + adst.y; e1 = e1 > 0.f ? e1 : 0.2f * e1;
      float e2 = a.z + adst.z; e2 = e2 > 0.f ? e2 : 0.2f * e2;
      float e3 = a.w + adst.w; e3 = e3 > 0.f ? e3 : 0.2f * e3;
      w4 = make_float4(__expf(e0), __expf(e1), __expf(e2), __expf(e3));
    }
    s_sh[wv][lane] = s;
    *(float4*)(&w_sh[wv][lane * 4]) = w4;
    asm volatile("s_waitcnt lgkmcnt(0)" ::: "memory");

    const float* wrow = &w_sh[wv][hd];
    const int*   srow = &s_sh[wv][0];
    int j = 0;
    for (; j + 4 <= nc; j += 4) {
      int sj0 = srow[j], sj1 = srow[j + 1], sj2 = srow[j + 2], sj3 = srow[j + 3];
      float w0 = wrow[4 * j],      w1 = wrow[4 * j + 4];
      float w2 = wrow[4 * j + 8],  w3 = wrow[4 * j + 12];
      ushort4 u0 = *(const ushort4*)(hbase + ((size_t)((uint)sj0 << 9)));
      ushort4 u1 = *(const ushort4*)(hbase + ((size_t)((uint)sj1 << 9)));
      ushort4 u2 = *(const ushort4*)(hbase + ((size_t)((uint)sj2 << 9)));
      ushort4 u3 = *(const ushort4*)(hbase + ((size_t)((uint)sj3 << 9)));
      wsum += w0 + w1 + w2 + w3;
      acc.x += w0 * bf2f(u0.x); acc.y += w0 * bf2f(u0.y);
      acc.z += w0 * bf2f(u0.z); acc.w += w0 * bf2f(u0.w);
      acc.x += w1 * bf2f(u1.x); acc.y += w1 * bf2f(u1.y);
      acc.z += w1 * bf2f(u1.z); acc.w += w1 * bf2f(u1.w);
      acc.x += w2 * bf2f(u2.x); acc.y += w2 * bf2f(u2.y);
      acc.z += w2 * bf2f(u2.z); acc.w += w2 * bf2f(u2.w);
      acc.x += w3 * bf2f(u3.x); acc.y += w3 * bf2f(u3.y);
      acc.z += w3 * bf2f(u3.z); acc.w += w3 * bf2f(u3.w);
    }
    for (; j < nc; j++) {
      int sj = srow[j];
      float ww = wrow[4 * j];
      ushort4 u = *(const ushort4*)(hbase + ((size_t)((uint)sj << 9)));
      wsum += ww;
      acc.x += ww * bf2f(u.x); acc.y += ww * bf2f(u.y);
      acc.z += ww * bf2f(u.z); acc.w += ww * bf2f(u.w);
    }
  }

  float inv = 1.0f / wsum;  // deg>=1 via self-loop
  float4 v = make_float4(acc.x * inv, acc.y * inv, acc.z * inv, acc.w * inv);

  if (LAYER == 1) {
    const float4 bv = *(const float4*)(bias + lane * 4);
    v.x = fmaxf(v.x + bv.x, 0.f);
    v.y = fmaxf(v.y + bv.y, 0.f);
    v.z = fmaxf(v.z + bv.z, 0.f);
    v.w = fmaxf(v.w + bv.w, 0.f);
    ushort4 h, l;
    h.x = f2bf(v.x); l.x = f2bf(v.x - bf2f(h.x));
    h.y = f2bf(v.y); l.y = f2bf(v.y - bf2f(h.y));
    h.z = f2bf(v.z); l.z = f2bf(v.z - bf2f(h.z));
    h.w = f2bf(v.w); l.w = f2bf(v.w - bf2f(h.w));
    const size_t o = (size_t)node * 256 + lane * 4;
    *(ushort4*)(out_h + o) = h;
    *(ushort4*)(out_l + o) = l;
  } else {
    // fused finale: head-mean + bias + relu + softmax(64)
    v.x += __shfl_xor(v.x, 16); v.y += __shfl_xor(v.y, 16);
    v.z += __shfl_xor(v.z, 16); v.w += __shfl_xor(v.w, 16);
    v.x += __shfl_xor(v.x, 32); v.y += __shfl_xor(v.y, 32);
    v.z += __shfl_xor(v.z, 32); v.w += __shfl_xor(v.w, 32);
    const int c4 = (lane & 15) * 4;
    const float4 bv = *(const float4*)(bias + c4);
    v.x = fmaxf(v.x * 0.25f + bv.x, 0.f);
    v.y = fmaxf(v.y * 0.25f + bv.y, 0.f);
    v.z = fmaxf(v.z * 0.25f + bv.z, 0.f);
    v.w = fmaxf(v.w * 0.25f + bv.w, 0.f);
    float mx = fmaxf(fmaxf(v.x, v.y), fmaxf(v.z, v.w));
    for (int off = 8; off >= 1; off >>= 1) mx = fmaxf(mx, __shfl_xor(mx, off));
    v.x = __expf(v.x - mx); v.y = __expf(v.y - mx);
    v.z = __expf(v.z - mx); v.w = __expf(v.w - mx);
    float sum = v.x + v.y + v.z + v.w;
    for (int off = 8; off >= 1; off >>= 1) sum += __shfl_xor(sum, off);
    float is = 1.0f / sum;
    v.x *= is; v.y *= is; v.z *= is; v.w *= is;
    if (lane < 16) *(float4*)(outp + (size_t)node * 64 + c4) = v;
  }
}

// ---------------------------------------------------------------------------

extern "C" void kernel_launch(void* const* d_in, const int* in_sizes, int n_in,
                              void* d_out, int out_size, void* d_ws, size_t ws_size,
                              hipStream_t stream) {
  const float* x   = (const float*)d_in[0];
  const int*   ei  = (const int*)d_in[1];
  const float* W1  = (const float*)d_in[2];
  const float* as1 = (const float*)d_in[3];
  const float* ad1 = (const float*)d_in[4];
  const float* b1  = (const float*)d_in[5];
  const float* W2  = (const float*)d_in[6];
  const float* as2 = (const float*)d_in[7];
  const float* ad2 = (const float*)d_in[8];
  const float* b2  = (const float*)d_in[9];
  float* out = (float*)d_out;

  const int N = in_sizes[0] / 128;
  const int E = in_sizes[1] / 2;
  int* srcv_p = (int*)ei;
  int* dstv_p = (int*)(ei + E);
  float* W1_p = (float*)W1;
  float* W2_p = (float*)W2;

  // ---- workspace layout
  ushort* h1   = (ushort*)d_ws;                   // [N,256] bf16 (also h2)
  ushort* hb_h = h1 + (size_t)N * 256;            // [N,256] bf16
  ushort* hb_l = hb_h + (size_t)N * 256;          // [N,256] bf16
  ushort* w1th = hb_l + (size_t)N * 256;          // [256][128] x2
  ushort* w1tl = w1th + 256 * 128;
  ushort* w2th = w1tl + 256 * 128;                // [256][256] x2
  ushort* w2tl = w2th + 256 * 256;
  float*  zbuf = (float*)(w2tl + 256 * 256);      // a_s1,a_d1,a_s2,a_d2 [16N]
  float* a_s1 = zbuf;
  float* a_d1 = a_s1 + (size_t)N * 4;
  float* a_s2 = a_d1 + (size_t)N * 4;
  float* a_d2 = a_s2 + (size_t)N * 4;
  int* rowptr = (int*)(zbuf + (size_t)N * 16);    // [N+1] (+pad)
  int* cnt    = rowptr + (N + 4);                 // [N]
  int* bar    = cnt + N;                          // [4]  (memset region)
  int* bsum   = bar + 4;                          // [256]
  int* cursor = bsum + 256;                       // [N]
  int* colx   = cursor + N;                       // [E]

  const int nb = (N + 255) / 256;  // 196 blocks — co-resident (cooperative)

  hipMemsetAsync(bar, 0, 4 * sizeof(int), stream);
  {
    int Nv = N, Ev = E;
    void* args[] = {&srcv_p, &dstv_p, &W1_p, &W2_p,
                    &w1th, &w1tl, &w2th, &w2tl,
                    &cnt, &rowptr, &cursor, &colx, &bsum, &bar, &Nv, &Ev};
    hipLaunchCooperativeKernel((const void*)k_csr_all, dim3(nb), dim3(256),
                               args, 0, stream);
  }

  // XCD-aligned swizzled 1-D grid: 16 blocks per group of 8 row blocks
  const int nrb = (N + 127) / 128;
  const int gemm_blocks = ((nrb + 7) / 8) * 16;
  const int wb = (N + 3) / 4;  // one wave per node

  k_gemm_mfma<1><<<gemm_blocks, 256, 0, stream>>>(x, nullptr, w1th, w1tl,
                                                  h1, N, 128,
                                                  as1, ad1, a_s1, a_d1);
  k_aggr<1><<<wb, 256, 0, stream>>>(h1, rowptr, colx, a_s1, a_d1, b1,
                                    hb_h, hb_l, nullptr, N);
  k_gemm_mfma<0><<<gemm_blocks, 256, 0, stream>>>(hb_h, hb_l, w2th, w2tl,
                                                  h1, N, 256,
                                                  as2, ad2, a_s2, a_d2);
  k_aggr<2><<<wb, 256, 0, stream>>>(h1, rowptr, colx, a_s2, a_d2, b2,
                                    nullptr, nullptr, out, N);
}

// Round 16
// 373.189 us; speedup vs baseline: 1.2311x; 1.1761x over previous
//
#include <hip/hip_runtime.h>

// ---------------------------------------------------------------------------
// 2-layer GAT (PyG GATConv), MI355X.
// R16: back to R12 internals (best: 405.8us); CSR cost attacked with
//      CONCURRENCY not barriers (R15: any grid-wide barrier ~25us x4).
//      Independent work fused by blockIdx branching:
//        K_prep_hist   = prep_w blocks  U  hist blocks      (independent)
//        K_gemm1_scat  = gemm1 blocks (first) U scatter blocks (backfill
//                        spare wave slots while gemm1 runs)
//      Chain: memset -> prep+hist -> scan -> gemm1+scatter -> aggr1 ->
//             gemm2 -> aggr2  (7 dispatches). No numeric changes.
// ---------------------------------------------------------------------------

typedef __attribute__((ext_vector_type(8))) short short8;
typedef __attribute__((ext_vector_type(4))) float f32x4;

static __device__ __forceinline__ ushort f2bf(float f) {  // RNE
  uint u = __float_as_uint(f);
  return (ushort)((u + 0x7FFFu + ((u >> 16) & 1u)) >> 16);
}
static __device__ __forceinline__ float bf2f(ushort s) {
  return __uint_as_float(((uint)s) << 16);
}
static __device__ __forceinline__ void split8(const float4& a, const float4& b,
                                              uint4& hh, uint4& ll) {
  ushort h0 = f2bf(a.x), h1 = f2bf(a.y), h2 = f2bf(a.z), h3 = f2bf(a.w);
  ushort h4 = f2bf(b.x), h5 = f2bf(b.y), h6 = f2bf(b.z), h7 = f2bf(b.w);
  hh.x = (uint)h0 | ((uint)h1 << 16); hh.y = (uint)h2 | ((uint)h3 << 16);
  hh.z = (uint)h4 | ((uint)h5 << 16); hh.w = (uint)h6 | ((uint)h7 << 16);
  ll.x = (uint)f2bf(a.x - bf2f(h0)) | ((uint)f2bf(a.y - bf2f(h1)) << 16);
  ll.y = (uint)f2bf(a.z - bf2f(h2)) | ((uint)f2bf(a.w - bf2f(h3)) << 16);
  ll.z = (uint)f2bf(b.x - bf2f(h4)) | ((uint)f2bf(b.y - bf2f(h5)) << 16);
  ll.w = (uint)f2bf(b.z - bf2f(h6)) | ((uint)f2bf(b.w - bf2f(h7)) << 16);
}

// ------------------ fused weight-prep + dst histogram ----------------------
__global__ __launch_bounds__(256)
void k_prep_hist(const float* __restrict__ W1, const float* __restrict__ W2,
                 ushort* __restrict__ w1th, ushort* __restrict__ w1tl,
                 ushort* __restrict__ w2th, ushort* __restrict__ w2tl,
                 const int* __restrict__ dstv, int* __restrict__ cnt, int E) {
  const int b = blockIdx.x;
  if (b < 128) {  // W1 [128][256] -> [256][128] split
    int gid = b * 256 + threadIdx.x;
    int c = gid & 255, k = gid >> 8;
    float w = W1[(size_t)k * 256 + c];
    ushort h = f2bf(w);
    w1th[(size_t)c * 128 + k] = h;
    w1tl[(size_t)c * 128 + k] = f2bf(w - bf2f(h));
  } else if (b < 384) {  // W2 [256][256] -> [256][256] split
    int gid = (b - 128) * 256 + threadIdx.x;
    int c = gid & 255, k = gid >> 8;
    float w = W2[(size_t)k * 256 + c];
    ushort h = f2bf(w);
    w2th[(size_t)c * 256 + k] = h;
    w2tl[(size_t)c * 256 + k] = f2bf(w - bf2f(h));
  } else {  // histogram of dst
    int i = (b - 384) * 256 + threadIdx.x;
    if (i < E) atomicAdd(&cnt[dstv[i]], 1);
  }
}

// Single-pass exclusive scan with decoupled lookback (grid <= 256 blocks).
__global__ __launch_bounds__(256)
void k_scan(const int* __restrict__ cnt, int* __restrict__ rowptr,
            int* __restrict__ cursor, int* __restrict__ bsum,
            int* __restrict__ bflag, int N, int E) {
  __shared__ int sm[256];
  __shared__ int s_prev;
  const int b = blockIdx.x, tid = threadIdx.x;
  const int gid = b * 256 + tid;
  int v = (gid < N) ? cnt[gid] : 0;
  sm[tid] = v;
  __syncthreads();
  for (int off = 1; off < 256; off <<= 1) {
    int t = (tid >= off) ? sm[tid - off] : 0;
    __syncthreads();
    sm[tid] += t;
    __syncthreads();
  }
  if (tid == 255) {
    atomicExch(&bsum[b], sm[255]);
    __threadfence();
    atomicExch(&bflag[b], 1);
  }
  if (tid == 0) s_prev = 0;
  __syncthreads();
  if (tid < b) {
    while (atomicAdd(&bflag[tid], 0) == 0) {}
    atomicAdd(&s_prev, atomicAdd(&bsum[tid], 0));
  }
  __syncthreads();
  if (gid < N) {
    int rp = s_prev + sm[tid] - v;
    rowptr[gid] = rp;
    cursor[gid] = rp;
  }
  if (gid == 0) rowptr[N] = E;
}

// ----------------------------- MFMA GEMM body (R12) ------------------------
// C[N,256] = (Ah+Al)[N,K] @ (Bh+Bl)[K,256], Bt stored [256][K].
// SPLIT=1: A fp32, split inline during LDS staging. SPLIT=0: pre-split bf16.
// B fragments direct from global (L1/L2-hot panel); LDS holds A only.
// XCD-aligned swizzle: col-halves of a row block differ by 8 block ids.
template <int SPLIT>
static __device__ __forceinline__
void gemm_body(int bid, const void* __restrict__ Aany,
               const ushort* __restrict__ Al_,
               const ushort* __restrict__ Bth, const ushort* __restrict__ Btl,
               ushort* __restrict__ hout, int Nrows, int K,
               const float* __restrict__ att_s, const float* __restrict__ att_d,
               float* __restrict__ a_s, float* __restrict__ a_d) {
  __shared__ ushort As_h[128][40];
  __shared__ ushort As_l[128][40];

  const int nrb = (Nrows + 127) >> 7;
  const int rb = (bid >> 4) * 8 + (bid & 7);
  const int ch = (bid >> 3) & 1;
  if (rb >= nrb) return;
  const int row0 = rb * 128;
  const int col0 = ch * 128;

  const int t = threadIdx.x;
  const int lane = t & 63;
  const int w = t >> 6;
  const int wr = (w >> 1) * 64;
  const int wc = (w & 1) * 64;
  const int lrow = t >> 2;       // 0..63 staging row index
  const int kc = (t & 3) * 8;    // k-chunk within BK=32

  const float*  Af = (const float*)Aany;    // SPLIT=1
  const ushort* Ah = (const ushort*)Aany;   // SPLIT=0

  f32x4 acc[4][4] = {};

  float4 pf[2][2];
  uint4 pa_h[2], pa_l[2];
  const uint4 z4 = make_uint4(0, 0, 0, 0);
#pragma unroll
  for (int p = 0; p < 2; p++) {
    int gr = row0 + p * 64 + lrow;
    if (SPLIT) {
      if (gr < Nrows) {
        const float* ap = Af + (size_t)gr * K + kc;
        pf[p][0] = *(const float4*)(ap);
        pf[p][1] = *(const float4*)(ap + 4);
      } else {
        pf[p][0] = make_float4(0.f, 0.f, 0.f, 0.f);
        pf[p][1] = pf[p][0];
      }
    } else {
      if (gr < Nrows) {
        pa_h[p] = *(const uint4*)(Ah + (size_t)gr * K + kc);
        pa_l[p] = *(const uint4*)(Al_ + (size_t)gr * K + kc);
      } else { pa_h[p] = z4; pa_l[p] = z4; }
    }
  }

  const int fr = lane & 15;
  const int fq = lane >> 4;
  const ushort* bb_h = Bth + (size_t)(col0 + wc + fr) * K + fq * 8;
  const ushort* bb_l = Btl + (size_t)(col0 + wc + fr) * K + fq * 8;

  for (int k0 = 0; k0 < K; k0 += 32) {
#pragma unroll
    for (int p = 0; p < 2; p++) {
      uint4 hh, ll;
      if (SPLIT) split8(pf[p][0], pf[p][1], hh, ll);
      else { hh = pa_h[p]; ll = pa_l[p]; }
      *(uint4*)(&As_h[p * 64 + lrow][kc]) = hh;
      *(uint4*)(&As_l[p * 64 + lrow][kc]) = ll;
    }
    __syncthreads();

    if (k0 + 32 < K) {
#pragma unroll
      for (int p = 0; p < 2; p++) {
        int gr = row0 + p * 64 + lrow;
        if (SPLIT) {
          if (gr < Nrows) {
            const float* ap = Af + (size_t)gr * K + k0 + 32 + kc;
            pf[p][0] = *(const float4*)(ap);
            pf[p][1] = *(const float4*)(ap + 4);
          } else {
            pf[p][0] = make_float4(0.f, 0.f, 0.f, 0.f);
            pf[p][1] = pf[p][0];
          }
        } else {
          if (gr < Nrows) {
            pa_h[p] = *(const uint4*)(Ah + (size_t)gr * K + k0 + 32 + kc);
            pa_l[p] = *(const uint4*)(Al_ + (size_t)gr * K + k0 + 32 + kc);
          } else { pa_h[p] = z4; pa_l[p] = z4; }
        }
      }
    }

    short8 fb_h[4], fb_l[4];
#pragma unroll
    for (int c = 0; c < 4; c++) {
      fb_h[c] = *(const short8*)(bb_h + (size_t)c * 16 * K + k0);
      fb_l[c] = *(const short8*)(bb_l + (size_t)c * 16 * K + k0);
    }
    short8 fa_h[4], fa_l[4];
#pragma unroll
    for (int r = 0; r < 4; r++) {
      fa_h[r] = *(const short8*)(&As_h[wr + r * 16 + fr][fq * 8]);
      fa_l[r] = *(const short8*)(&As_l[wr + r * 16 + fr][fq * 8]);
    }
#pragma unroll
    for (int r = 0; r < 4; r++)
#pragma unroll
      for (int c = 0; c < 4; c++) {
        acc[r][c] = __builtin_amdgcn_mfma_f32_16x16x32_bf16(fa_h[r], fb_h[c], acc[r][c], 0, 0, 0);
        acc[r][c] = __builtin_amdgcn_mfma_f32_16x16x32_bf16(fa_l[r], fb_h[c], acc[r][c], 0, 0, 0);
        acc[r][c] = __builtin_amdgcn_mfma_f32_16x16x32_bf16(fa_h[r], fb_l[c], acc[r][c], 0, 0, 0);
      }
    __syncthreads();
  }

  // ---- C write (bf16, direct — L2 absorbs the 2B scatter)
#pragma unroll
  for (int r = 0; r < 4; r++)
#pragma unroll
    for (int c = 0; c < 4; c++) {
      int colg = col0 + wc + c * 16 + fr;
#pragma unroll
      for (int reg = 0; reg < 4; reg++) {
        int gr = row0 + wr + r * 16 + fq * 4 + reg;
        if (gr < Nrows) hout[(size_t)gr * 256 + colg] = f2bf(acc[r][c][reg]);
      }
    }

  // ---- attention scores: wave's 64 cols = one head (wc 64-aligned)
  const int head = (col0 + wc) >> 6;
  float asv[4], adv[4];
#pragma unroll
  for (int c = 0; c < 4; c++) {
    asv[c] = att_s[col0 + wc + c * 16 + fr];
    adv[c] = att_d[col0 + wc + c * 16 + fr];
  }
#pragma unroll
  for (int r = 0; r < 4; r++)
#pragma unroll
    for (int reg = 0; reg < 4; reg++) {
      float ps = 0.f, pd = 0.f;
#pragma unroll
      for (int c = 0; c < 4; c++) {
        ps += acc[r][c][reg] * asv[c];
        pd += acc[r][c][reg] * adv[c];
      }
      ps += __shfl_xor(ps, 1); pd += __shfl_xor(pd, 1);
      ps += __shfl_xor(ps, 2); pd += __shfl_xor(pd, 2);
      ps += __shfl_xor(ps, 4); pd += __shfl_xor(pd, 4);
      ps += __shfl_xor(ps, 8); pd += __shfl_xor(pd, 8);
      if (fr == 0) {
        int gr = row0 + wr + r * 16 + fq * 4 + reg;
        if (gr < Nrows) {
          a_s[(size_t)gr * 4 + head] = ps;
          a_d[(size_t)gr * 4 + head] = pd;
        }
      }
    }
}

// ---- fused: gemm1 blocks first, CSR scatter blocks backfill spare slots ----
__global__ __launch_bounds__(256)
void k_gemm1_scatter(const float* __restrict__ x,
                     const ushort* __restrict__ Bth,
                     const ushort* __restrict__ Btl,
                     ushort* __restrict__ hout, int Nrows,
                     const float* __restrict__ att_s,
                     const float* __restrict__ att_d,
                     float* __restrict__ a_s, float* __restrict__ a_d,
                     const int* __restrict__ srcv, const int* __restrict__ dstv,
                     int* __restrict__ cursor, int* __restrict__ col,
                     int E, int gemm_blocks) {
  if ((int)blockIdx.x < gemm_blocks) {
    gemm_body<1>(blockIdx.x, x, nullptr, Bth, Btl, hout, Nrows, 128,
                 att_s, att_d, a_s, a_d);
  } else {
    int i = ((int)blockIdx.x - gemm_blocks) * 256 + threadIdx.x;
    if (i < E) {
      int p = atomicAdd(&cursor[dstv[i]], 1);
      col[p] = srcv[i];
    }
  }
}

__global__ __launch_bounds__(256)
void k_gemm2(const ushort* __restrict__ Ah, const ushort* __restrict__ Al_,
             const ushort* __restrict__ Bth, const ushort* __restrict__ Btl,
             ushort* __restrict__ hout, int Nrows,
             const float* __restrict__ att_s, const float* __restrict__ att_d,
             float* __restrict__ a_s, float* __restrict__ a_d) {
  gemm_body<0>(blockIdx.x, Ah, Al_, Bth, Btl, hout, Nrows, 256,
               att_s, att_d, a_s, a_d);
}

// ----------------------------- aggregation ---------------------------------
// ONE wave per node; lane owns channels [4*lane, 4*lane+3] (ushort4 gather),
// head = lane>>4. Chunk of 64 edges: lane gathers a_s[col] float4, computes
// all-head weights inline, stages (src, w[4]) in LDS. Denominator free.
// LAYER 1: relu(acc/den + bias) -> split bf16 (out_h, out_l).
// LAYER 2: fused finale — head-mean + bias + relu + softmax(64) -> outp.
template <int LAYER>
__global__ __launch_bounds__(256)
void k_aggr(const ushort* __restrict__ hsrc, const int* __restrict__ rowptr,
            const int* __restrict__ col, const float* __restrict__ a_s,
            const float* __restrict__ a_d, const float* __restrict__ bias,
            ushort* __restrict__ out_h, ushort* __restrict__ out_l,
            float* __restrict__ outp, int N) {
  __shared__ int   s_sh[4][64];
  __shared__ float w_sh[4][256];
  const int wv = threadIdx.x >> 6;
  const int lane = threadIdx.x & 63;
  const int node = blockIdx.x * 4 + wv;
  if (node >= N) return;
  const int hd = lane >> 4;
  const int beg = rowptr[node], end = rowptr[node + 1];
  const float4 adst = *(const float4*)(a_d + (size_t)node * 4);

  float4 acc = make_float4(0.f, 0.f, 0.f, 0.f);
  float wsum = 0.f;
  const char* hbase = (const char*)(hsrc + lane * 4);

  for (int c0 = beg; c0 < end; c0 += 64) {
    int nc = min(64, end - c0);
    int s = 0;
    float4 w4 = make_float4(0.f, 0.f, 0.f, 0.f);
    if (lane < nc) {
      s = col[c0 + lane];
      float4 a = *(const float4*)(a_s + (size_t)s * 4);
      float e0 = a.x + adst.x; e0 = e0 > 0.f ? e0 : 0.2f * e0;
      float e1 = a.y + adst.y; e1 = e1 > 0.f ? e1 : 0.2f * e1;
      float e2 = a.z + adst.z; e2 = e2 > 0.f ? e2 : 0.2f * e2;
      float e3 = a.w + adst.w; e3 = e3 > 0.f ? e3 : 0.2f * e3;
      w4 = make_float4(__expf(e0), __expf(e1), __expf(e2), __expf(e3));
    }
    s_sh[wv][lane] = s;
    *(float4*)(&w_sh[wv][lane * 4]) = w4;
    asm volatile("s_waitcnt lgkmcnt(0)" ::: "memory");

    const float* wrow = &w_sh[wv][hd];
    const int*   srow = &s_sh[wv][0];
    int j = 0;
    for (; j + 4 <= nc; j += 4) {
      int sj0 = srow[j], sj1 = srow[j + 1], sj2 = srow[j + 2], sj3 = srow[j + 3];
      float w0 = wrow[4 * j],      w1 = wrow[4 * j + 4];
      float w2 = wrow[4 * j + 8],  w3 = wrow[4 * j + 12];
      ushort4 u0 = *(const ushort4*)(hbase + ((size_t)((uint)sj0 << 9)));
      ushort4 u1 = *(const ushort4*)(hbase + ((size_t)((uint)sj1 << 9)));
      ushort4 u2 = *(const ushort4*)(hbase + ((size_t)((uint)sj2 << 9)));
      ushort4 u3 = *(const ushort4*)(hbase + ((size_t)((uint)sj3 << 9)));
      wsum += w0 + w1 + w2 + w3;
      acc.x += w0 * bf2f(u0.x); acc.y += w0 * bf2f(u0.y);
      acc.z += w0 * bf2f(u0.z); acc.w += w0 * bf2f(u0.w);
      acc.x += w1 * bf2f(u1.x); acc.y += w1 * bf2f(u1.y);
      acc.z += w1 * bf2f(u1.z); acc.w += w1 * bf2f(u1.w);
      acc.x += w2 * bf2f(u2.x); acc.y += w2 * bf2f(u2.y);
      acc.z += w2 * bf2f(u2.z); acc.w += w2 * bf2f(u2.w);
      acc.x += w3 * bf2f(u3.x); acc.y += w3 * bf2f(u3.y);
      acc.z += w3 * bf2f(u3.z); acc.w += w3 * bf2f(u3.w);
    }
    for (; j < nc; j++) {
      int sj = srow[j];
      float ww = wrow[4 * j];
      ushort4 u = *(const ushort4*)(hbase + ((size_t)((uint)sj << 9)));
      wsum += ww;
      acc.x += ww * bf2f(u.x); acc.y += ww * bf2f(u.y);
      acc.z += ww * bf2f(u.z); acc.w += ww * bf2f(u.w);
    }
  }

  float inv = 1.0f / wsum;  // deg>=1 via self-loop
  float4 v = make_float4(acc.x * inv, acc.y * inv, acc.z * inv, acc.w * inv);

  if (LAYER == 1) {
    const float4 bv = *(const float4*)(bias + lane * 4);
    v.x = fmaxf(v.x + bv.x, 0.f);
    v.y = fmaxf(v.y + bv.y, 0.f);
    v.z = fmaxf(v.z + bv.z, 0.f);
    v.w = fmaxf(v.w + bv.w, 0.f);
    ushort4 h, l;
    h.x = f2bf(v.x); l.x = f2bf(v.x - bf2f(h.x));
    h.y = f2bf(v.y); l.y = f2bf(v.y - bf2f(h.y));
    h.z = f2bf(v.z); l.z = f2bf(v.z - bf2f(h.z));
    h.w = f2bf(v.w); l.w = f2bf(v.w - bf2f(h.w));
    const size_t o = (size_t)node * 256 + lane * 4;
    *(ushort4*)(out_h + o) = h;
    *(ushort4*)(out_l + o) = l;
  } else {
    // fused finale: head-mean + bias + relu + softmax(64)
    v.x += __shfl_xor(v.x, 16); v.y += __shfl_xor(v.y, 16);
    v.z += __shfl_xor(v.z, 16); v.w += __shfl_xor(v.w, 16);
    v.x += __shfl_xor(v.x, 32); v.y += __shfl_xor(v.y, 32);
    v.z += __shfl_xor(v.z, 32); v.w += __shfl_xor(v.w, 32);
    const int c4 = (lane & 15) * 4;
    const float4 bv = *(const float4*)(bias + c4);
    v.x = fmaxf(v.x * 0.25f + bv.x, 0.f);
    v.y = fmaxf(v.y * 0.25f + bv.y, 0.f);
    v.z = fmaxf(v.z * 0.25f + bv.z, 0.f);
    v.w = fmaxf(v.w * 0.25f + bv.w, 0.f);
    float mx = fmaxf(fmaxf(v.x, v.y), fmaxf(v.z, v.w));
    for (int off = 8; off >= 1; off >>= 1) mx = fmaxf(mx, __shfl_xor(mx, off));
    v.x = __expf(v.x - mx); v.y = __expf(v.y - mx);
    v.z = __expf(v.z - mx); v.w = __expf(v.w - mx);
    float sum = v.x + v.y + v.z + v.w;
    for (int off = 8; off >= 1; off >>= 1) sum += __shfl_xor(sum, off);
    float is = 1.0f / sum;
    v.x *= is; v.y *= is; v.z *= is; v.w *= is;
    if (lane < 16) *(float4*)(outp + (size_t)node * 64 + c4) = v;
  }
}

// ---------------------------------------------------------------------------

extern "C" void kernel_launch(void* const* d_in, const int* in_sizes, int n_in,
                              void* d_out, int out_size, void* d_ws, size_t ws_size,
                              hipStream_t stream) {
  const float* x   = (const float*)d_in[0];
  const int*   ei  = (const int*)d_in[1];
  const float* W1  = (const float*)d_in[2];
  const float* as1 = (const float*)d_in[3];
  const float* ad1 = (const float*)d_in[4];
  const float* b1  = (const float*)d_in[5];
  const float* W2  = (const float*)d_in[6];
  const float* as2 = (const float*)d_in[7];
  const float* ad2 = (const float*)d_in[8];
  const float* b2  = (const float*)d_in[9];
  float* out = (float*)d_out;

  const int N = in_sizes[0] / 128;
  const int E = in_sizes[1] / 2;
  const int* srcv = ei;
  const int* dstv = ei + E;

  // ---- workspace layout
  ushort* h1   = (ushort*)d_ws;                   // [N,256] bf16 (also h2)
  ushort* hb_h = h1 + (size_t)N * 256;            // [N,256] bf16
  ushort* hb_l = hb_h + (size_t)N * 256;          // [N,256] bf16
  ushort* w1th = hb_l + (size_t)N * 256;          // [256][128] x2
  ushort* w1tl = w1th + 256 * 128;
  ushort* w2th = w1tl + 256 * 128;                // [256][256] x2
  ushort* w2tl = w2th + 256 * 256;
  float*  zbuf = (float*)(w2tl + 256 * 256);      // a_s1,a_d1,a_s2,a_d2 [16N]
  float* a_s1 = zbuf;
  float* a_d1 = a_s1 + (size_t)N * 4;
  float* a_s2 = a_d1 + (size_t)N * 4;
  float* a_d2 = a_s2 + (size_t)N * 4;
  int* rowptr = (int*)(zbuf + (size_t)N * 16);    // [N+1] (+pad)
  int* cnt    = rowptr + (N + 4);                 // [N]      (memset region)
  int* bflag  = cnt + N;                          // [256]    (memset region)
  int* bsum   = bflag + 256;                      // [256]
  int* cursor = bsum + 256;                       // [N]
  int* colx   = cursor + N;                       // [E]

  const int nb = (N + 255) / 256;  // <=256 required by k_scan lookback
  const int eb = (E + 255) / 256;

  // XCD-aligned swizzled 1-D grid: 16 blocks per group of 8 row blocks
  const int nrb = (N + 127) / 128;
  const int gemm_blocks = ((nrb + 7) / 8) * 16;
  const int wb = (N + 3) / 4;  // one wave per node

  hipMemsetAsync(cnt, 0, ((size_t)N + 256) * 4, stream);  // cnt + bflag
  k_prep_hist<<<384 + eb, 256, 0, stream>>>(W1, W2, w1th, w1tl, w2th, w2tl,
                                            dstv, cnt, E);
  k_scan<<<nb, 256, 0, stream>>>(cnt, rowptr, cursor, bsum, bflag, N, E);
  k_gemm1_scatter<<<gemm_blocks + eb, 256, 0, stream>>>(
      x, w1th, w1tl, h1, N, as1, ad1, a_s1, a_d1,
      srcv, dstv, cursor, colx, E, gemm_blocks);
  k_aggr<1><<<wb, 256, 0, stream>>>(h1, rowptr, colx, a_s1, a_d1, b1,
                                    hb_h, hb_l, nullptr, N);
  k_gemm2<<<gemm_blocks, 256, 0, stream>>>(hb_h, hb_l, w2th, w2tl, h1, N,
                                           as2, ad2, a_s2, a_d2);
  k_aggr<2><<<wb, 256, 0, stream>>>(h1, rowptr, colx, a_s2, a_d2, b2,
                                    nullptr, nullptr, out, N);
}

// Round 17
// 360.166 us; speedup vs baseline: 1.2756x; 1.0362x over previous
//
#include <hip/hip_runtime.h>

// ---------------------------------------------------------------------------
// 2-layer GAT (PyG GATConv), MI355X.
// R17 (from R16 = 373us best):
//   (1) De-atomized scatter: hist's atomicAdd return value IS the edge's
//       within-node slot -> stored as pe[i] during prep_hist (free), scatter
//       in the gemm1 window becomes non-atomic pure-BW
//       col[rowptr[dst]+pe] = src. (R16: 850k atomic RMWs added ~40us to
//       the fused gemm1 window.) cursor deleted.
//   (2) aggr j-loop unroll 4 -> 8 (deeper MLP; aggr is latency-bound at
//       VALU 43% / HBM 50% / occ 71%).
//   gemm internals / scan / layout otherwise unchanged.
// ---------------------------------------------------------------------------

typedef __attribute__((ext_vector_type(8))) short short8;
typedef __attribute__((ext_vector_type(4))) float f32x4;

static __device__ __forceinline__ ushort f2bf(float f) {  // RNE
  uint u = __float_as_uint(f);
  return (ushort)((u + 0x7FFFu + ((u >> 16) & 1u)) >> 16);
}
static __device__ __forceinline__ float bf2f(ushort s) {
  return __uint_as_float(((uint)s) << 16);
}
static __device__ __forceinline__ void split8(const float4& a, const float4& b,
                                              uint4& hh, uint4& ll) {
  ushort h0 = f2bf(a.x), h1 = f2bf(a.y), h2 = f2bf(a.z), h3 = f2bf(a.w);
  ushort h4 = f2bf(b.x), h5 = f2bf(b.y), h6 = f2bf(b.z), h7 = f2bf(b.w);
  hh.x = (uint)h0 | ((uint)h1 << 16); hh.y = (uint)h2 | ((uint)h3 << 16);
  hh.z = (uint)h4 | ((uint)h5 << 16); hh.w = (uint)h6 | ((uint)h7 << 16);
  ll.x = (uint)f2bf(a.x - bf2f(h0)) | ((uint)f2bf(a.y - bf2f(h1)) << 16);
  ll.y = (uint)f2bf(a.z - bf2f(h2)) | ((uint)f2bf(a.w - bf2f(h3)) << 16);
  ll.z = (uint)f2bf(b.x - bf2f(h4)) | ((uint)f2bf(b.y - bf2f(h5)) << 16);
  ll.w = (uint)f2bf(b.z - bf2f(h6)) | ((uint)f2bf(b.w - bf2f(h7)) << 16);
}

// ---------- fused weight-prep + dst histogram (+ per-edge slot pe) ---------
__global__ __launch_bounds__(256)
void k_prep_hist(const float* __restrict__ W1, const float* __restrict__ W2,
                 ushort* __restrict__ w1th, ushort* __restrict__ w1tl,
                 ushort* __restrict__ w2th, ushort* __restrict__ w2tl,
                 const int* __restrict__ dstv, int* __restrict__ cnt,
                 int* __restrict__ pe, int E) {
  const int b = blockIdx.x;
  if (b < 128) {  // W1 [128][256] -> [256][128] split
    int gid = b * 256 + threadIdx.x;
    int c = gid & 255, k = gid >> 8;
    float w = W1[(size_t)k * 256 + c];
    ushort h = f2bf(w);
    w1th[(size_t)c * 128 + k] = h;
    w1tl[(size_t)c * 128 + k] = f2bf(w - bf2f(h));
  } else if (b < 384) {  // W2 [256][256] -> [256][256] split
    int gid = (b - 128) * 256 + threadIdx.x;
    int c = gid & 255, k = gid >> 8;
    float w = W2[(size_t)k * 256 + c];
    ushort h = f2bf(w);
    w2th[(size_t)c * 256 + k] = h;
    w2tl[(size_t)c * 256 + k] = f2bf(w - bf2f(h));
  } else {  // histogram of dst; atomic return value = edge's slot
    int i = (b - 384) * 256 + threadIdx.x;
    if (i < E) pe[i] = atomicAdd(&cnt[dstv[i]], 1);
  }
}

// Single-pass exclusive scan with decoupled lookback (grid <= 256 blocks).
__global__ __launch_bounds__(256)
void k_scan(const int* __restrict__ cnt, int* __restrict__ rowptr,
            int* __restrict__ bsum, int* __restrict__ bflag, int N, int E) {
  __shared__ int sm[256];
  __shared__ int s_prev;
  const int b = blockIdx.x, tid = threadIdx.x;
  const int gid = b * 256 + tid;
  int v = (gid < N) ? cnt[gid] : 0;
  sm[tid] = v;
  __syncthreads();
  for (int off = 1; off < 256; off <<= 1) {
    int t = (tid >= off) ? sm[tid - off] : 0;
    __syncthreads();
    sm[tid] += t;
    __syncthreads();
  }
  if (tid == 255) {
    atomicExch(&bsum[b], sm[255]);
    __threadfence();
    atomicExch(&bflag[b], 1);
  }
  if (tid == 0) s_prev = 0;
  __syncthreads();
  if (tid < b) {
    while (atomicAdd(&bflag[tid], 0) == 0) {}
    atomicAdd(&s_prev, atomicAdd(&bsum[tid], 0));
  }
  __syncthreads();
  if (gid < N) rowptr[gid] = s_prev + sm[tid] - v;
  if (gid == 0) rowptr[N] = E;
}

// ----------------------------- MFMA GEMM body (R12) ------------------------
// C[N,256] = (Ah+Al)[N,K] @ (Bh+Bl)[K,256], Bt stored [256][K].
// SPLIT=1: A fp32, split inline during LDS staging. SPLIT=0: pre-split bf16.
// B fragments direct from global (L1/L2-hot panel); LDS holds A only.
// XCD-aligned swizzle: col-halves of a row block differ by 8 block ids.
template <int SPLIT>
static __device__ __forceinline__
void gemm_body(int bid, const void* __restrict__ Aany,
               const ushort* __restrict__ Al_,
               const ushort* __restrict__ Bth, const ushort* __restrict__ Btl,
               ushort* __restrict__ hout, int Nrows, int K,
               const float* __restrict__ att_s, const float* __restrict__ att_d,
               float* __restrict__ a_s, float* __restrict__ a_d) {
  __shared__ ushort As_h[128][40];
  __shared__ ushort As_l[128][40];

  const int nrb = (Nrows + 127) >> 7;
  const int rb = (bid >> 4) * 8 + (bid & 7);
  const int ch = (bid >> 3) & 1;
  if (rb >= nrb) return;
  const int row0 = rb * 128;
  const int col0 = ch * 128;

  const int t = threadIdx.x;
  const int lane = t & 63;
  const int w = t >> 6;
  const int wr = (w >> 1) * 64;
  const int wc = (w & 1) * 64;
  const int lrow = t >> 2;       // 0..63 staging row index
  const int kc = (t & 3) * 8;    // k-chunk within BK=32

  const float*  Af = (const float*)Aany;    // SPLIT=1
  const ushort* Ah = (const ushort*)Aany;   // SPLIT=0

  f32x4 acc[4][4] = {};

  float4 pf[2][2];
  uint4 pa_h[2], pa_l[2];
  const uint4 z4 = make_uint4(0, 0, 0, 0);
#pragma unroll
  for (int p = 0; p < 2; p++) {
    int gr = row0 + p * 64 + lrow;
    if (SPLIT) {
      if (gr < Nrows) {
        const float* ap = Af + (size_t)gr * K + kc;
        pf[p][0] = *(const float4*)(ap);
        pf[p][1] = *(const float4*)(ap + 4);
      } else {
        pf[p][0] = make_float4(0.f, 0.f, 0.f, 0.f);
        pf[p][1] = pf[p][0];
      }
    } else {
      if (gr < Nrows) {
        pa_h[p] = *(const uint4*)(Ah + (size_t)gr * K + kc);
        pa_l[p] = *(const uint4*)(Al_ + (size_t)gr * K + kc);
      } else { pa_h[p] = z4; pa_l[p] = z4; }
    }
  }

  const int fr = lane & 15;
  const int fq = lane >> 4;
  const ushort* bb_h = Bth + (size_t)(col0 + wc + fr) * K + fq * 8;
  const ushort* bb_l = Btl + (size_t)(col0 + wc + fr) * K + fq * 8;

  for (int k0 = 0; k0 < K; k0 += 32) {
#pragma unroll
    for (int p = 0; p < 2; p++) {
      uint4 hh, ll;
      if (SPLIT) split8(pf[p][0], pf[p][1], hh, ll);
      else { hh = pa_h[p]; ll = pa_l[p]; }
      *(uint4*)(&As_h[p * 64 + lrow][kc]) = hh;
      *(uint4*)(&As_l[p * 64 + lrow][kc]) = ll;
    }
    __syncthreads();

    if (k0 + 32 < K) {
#pragma unroll
      for (int p = 0; p < 2; p++) {
        int gr = row0 + p * 64 + lrow;
        if (SPLIT) {
          if (gr < Nrows) {
            const float* ap = Af + (size_t)gr * K + k0 + 32 + kc;
            pf[p][0] = *(const float4*)(ap);
            pf[p][1] = *(const float4*)(ap + 4);
          } else {
            pf[p][0] = make_float4(0.f, 0.f, 0.f, 0.f);
            pf[p][1] = pf[p][0];
          }
        } else {
          if (gr < Nrows) {
            pa_h[p] = *(const uint4*)(Ah + (size_t)gr * K + k0 + 32 + kc);
            pa_l[p] = *(const uint4*)(Al_ + (size_t)gr * K + k0 + 32 + kc);
          } else { pa_h[p] = z4; pa_l[p] = z4; }
        }
      }
    }

    short8 fb_h[4], fb_l[4];
#pragma unroll
    for (int c = 0; c < 4; c++) {
      fb_h[c] = *(const short8*)(bb_h + (size_t)c * 16 * K + k0);
      fb_l[c] = *(const short8*)(bb_l + (size_t)c * 16 * K + k0);
    }
    short8 fa_h[4], fa_l[4];
#pragma unroll
    for (int r = 0; r < 4; r++) {
      fa_h[r] = *(const short8*)(&As_h[wr + r * 16 + fr][fq * 8]);
      fa_l[r] = *(const short8*)(&As_l[wr + r * 16 + fr][fq * 8]);
    }
#pragma unroll
    for (int r = 0; r < 4; r++)
#pragma unroll
      for (int c = 0; c < 4; c++) {
        acc[r][c] = __builtin_amdgcn_mfma_f32_16x16x32_bf16(fa_h[r], fb_h[c], acc[r][c], 0, 0, 0);
        acc[r][c] = __builtin_amdgcn_mfma_f32_16x16x32_bf16(fa_l[r], fb_h[c], acc[r][c], 0, 0, 0);
        acc[r][c] = __builtin_amdgcn_mfma_f32_16x16x32_bf16(fa_h[r], fb_l[c], acc[r][c], 0, 0, 0);
      }
    __syncthreads();
  }

  // ---- C write (bf16, direct — L2 absorbs the 2B scatter)
#pragma unroll
  for (int r = 0; r < 4; r++)
#pragma unroll
    for (int c = 0; c < 4; c++) {
      int colg = col0 + wc + c * 16 + fr;
#pragma unroll
      for (int reg = 0; reg < 4; reg++) {
        int gr = row0 + wr + r * 16 + fq * 4 + reg;
        if (gr < Nrows) hout[(size_t)gr * 256 + colg] = f2bf(acc[r][c][reg]);
      }
    }

  // ---- attention scores: wave's 64 cols = one head (wc 64-aligned)
  const int head = (col0 + wc) >> 6;
  float asv[4], adv[4];
#pragma unroll
  for (int c = 0; c < 4; c++) {
    asv[c] = att_s[col0 + wc + c * 16 + fr];
    adv[c] = att_d[col0 + wc + c * 16 + fr];
  }
#pragma unroll
  for (int r = 0; r < 4; r++)
#pragma unroll
    for (int reg = 0; reg < 4; reg++) {
      float ps = 0.f, pd = 0.f;
#pragma unroll
      for (int c = 0; c < 4; c++) {
        ps += acc[r][c][reg] * asv[c];
        pd += acc[r][c][reg] * adv[c];
      }
      ps += __shfl_xor(ps, 1); pd += __shfl_xor(pd, 1);
      ps += __shfl_xor(ps, 2); pd += __shfl_xor(pd, 2);
      ps += __shfl_xor(ps, 4); pd += __shfl_xor(pd, 4);
      ps += __shfl_xor(ps, 8); pd += __shfl_xor(pd, 8);
      if (fr == 0) {
        int gr = row0 + wr + r * 16 + fq * 4 + reg;
        if (gr < Nrows) {
          a_s[(size_t)gr * 4 + head] = ps;
          a_d[(size_t)gr * 4 + head] = pd;
        }
      }
    }
}

// ---- fused: gemm1 blocks first, NON-ATOMIC scatter blocks backfill --------
__global__ __launch_bounds__(256)
void k_gemm1_scatter(const float* __restrict__ x,
                     const ushort* __restrict__ Bth,
                     const ushort* __restrict__ Btl,
                     ushort* __restrict__ hout, int Nrows,
                     const float* __restrict__ att_s,
                     const float* __restrict__ att_d,
                     float* __restrict__ a_s, float* __restrict__ a_d,
                     const int* __restrict__ srcv, const int* __restrict__ dstv,
                     const int* __restrict__ rowptr, const int* __restrict__ pe,
                     int* __restrict__ col, int E, int gemm_blocks) {
  if ((int)blockIdx.x < gemm_blocks) {
    gemm_body<1>(blockIdx.x, x, nullptr, Bth, Btl, hout, Nrows, 128,
                 att_s, att_d, a_s, a_d);
  } else {
    int i = ((int)blockIdx.x - gemm_blocks) * 256 + threadIdx.x;
    if (i < E) col[rowptr[dstv[i]] + pe[i]] = srcv[i];
  }
}

__global__ __launch_bounds__(256)
void k_gemm2(const ushort* __restrict__ Ah, const ushort* __restrict__ Al_,
             const ushort* __restrict__ Bth, const ushort* __restrict__ Btl,
             ushort* __restrict__ hout, int Nrows,
             const float* __restrict__ att_s, const float* __restrict__ att_d,
             float* __restrict__ a_s, float* __restrict__ a_d) {
  gemm_body<0>(blockIdx.x, Ah, Al_, Bth, Btl, hout, Nrows, 256,
               att_s, att_d, a_s, a_d);
}

// ----------------------------- aggregation ---------------------------------
// ONE wave per node; lane owns channels [4*lane, 4*lane+3] (ushort4 gather),
// head = lane>>4. Chunk of 64 edges: lane gathers a_s[col] float4, computes
// all-head weights inline, stages (src, w[4]) in LDS. j-loop unrolled 8 for
// MLP depth. Denominator accumulated free.
// LAYER 1: relu(acc/den + bias) -> split bf16 (out_h, out_l).
// LAYER 2: fused finale — head-mean + bias + relu + softmax(64) -> outp.
template <int LAYER>
__global__ __launch_bounds__(256)
void k_aggr(const ushort* __restrict__ hsrc, const int* __restrict__ rowptr,
            const int* __restrict__ col, const float* __restrict__ a_s,
            const float* __restrict__ a_d, const float* __restrict__ bias,
            ushort* __restrict__ out_h, ushort* __restrict__ out_l,
            float* __restrict__ outp, int N) {
  __shared__ int   s_sh[4][64];
  __shared__ float w_sh[4][256];
  const int wv = threadIdx.x >> 6;
  const int lane = threadIdx.x & 63;
  const int node = blockIdx.x * 4 + wv;
  if (node >= N) return;
  const int hd = lane >> 4;
  const int beg = rowptr[node], end = rowptr[node + 1];
  const float4 adst = *(const float4*)(a_d + (size_t)node * 4);

  float4 acc = make_float4(0.f, 0.f, 0.f, 0.f);
  float wsum = 0.f;
  const char* hbase = (const char*)(hsrc + lane * 4);

  for (int c0 = beg; c0 < end; c0 += 64) {
    int nc = min(64, end - c0);
    int s = 0;
    float4 w4 = make_float4(0.f, 0.f, 0.f, 0.f);
    if (lane < nc) {
      s = col[c0 + lane];
      float4 a = *(const float4*)(a_s + (size_t)s * 4);
      float e0 = a.x + adst.x; e0 = e0 > 0.f ? e0 : 0.2f * e0;
      float e1 = a.y + adst.y; e1 = e1 > 0.f ? e1 : 0.2f * e1;
      float e2 = a.z + adst.z; e2 = e2 > 0.f ? e2 : 0.2f * e2;
      float e3 = a.w + adst.w; e3 = e3 > 0.f ? e3 : 0.2f * e3;
      w4 = make_float4(__expf(e0), __expf(e1), __expf(e2), __expf(e3));
    }
    s_sh[wv][lane] = s;
    *(float4*)(&w_sh[wv][lane * 4]) = w4;
    asm volatile("s_waitcnt lgkmcnt(0)" ::: "memory");

    const float* wrow = &w_sh[wv][hd];
    const int*   srow = &s_sh[wv][0];
    int j = 0;
    for (; j + 8 <= nc; j += 8) {
      int sj0 = srow[j],     sj1 = srow[j + 1], sj2 = srow[j + 2], sj3 = srow[j + 3];
      int sj4 = srow[j + 4], sj5 = srow[j + 5], sj6 = srow[j + 6], sj7 = srow[j + 7];
      float w0 = wrow[4 * j],      w1 = wrow[4 * j + 4];
      float w2 = wrow[4 * j + 8],  w3 = wrow[4 * j + 12];
      float w4_ = wrow[4 * j + 16], w5 = wrow[4 * j + 20];
      float w6 = wrow[4 * j + 24], w7 = wrow[4 * j + 28];
      ushort4 u0 = *(const ushort4*)(hbase + ((size_t)((uint)sj0 << 9)));
      ushort4 u1 = *(const ushort4*)(hbase + ((size_t)((uint)sj1 << 9)));
      ushort4 u2 = *(const ushort4*)(hbase + ((size_t)((uint)sj2 << 9)));
      ushort4 u3 = *(const ushort4*)(hbase + ((size_t)((uint)sj3 << 9)));
      ushort4 u4 = *(const ushort4*)(hbase + ((size_t)((uint)sj4 << 9)));
      ushort4 u5 = *(const ushort4*)(hbase + ((size_t)((uint)sj5 << 9)));
      ushort4 u6 = *(const ushort4*)(hbase + ((size_t)((uint)sj6 << 9)));
      ushort4 u7 = *(const ushort4*)(hbase + ((size_t)((uint)sj7 << 9)));
      wsum += w0 + w1 + w2 + w3 + w4_ + w5 + w6 + w7;
      acc.x += w0 * bf2f(u0.x); acc.y += w0 * bf2f(u0.y);
      acc.z += w0 * bf2f(u0.z); acc.w += w0 * bf2f(u0.w);
      acc.x += w1 * bf2f(u1.x); acc.y += w1 * bf2f(u1.y);
      acc.z += w1 * bf2f(u1.z); acc.w += w1 * bf2f(u1.w);
      acc.x += w2 * bf2f(u2.x); acc.y += w2 * bf2f(u2.y);
      acc.z += w2 * bf2f(u2.z); acc.w += w2 * bf2f(u2.w);
      acc.x += w3 * bf2f(u3.x); acc.y += w3 * bf2f(u3.y);
      acc.z += w3 * bf2f(u3.z); acc.w += w3 * bf2f(u3.w);
      acc.x += w4_ * bf2f(u4.x); acc.y += w4_ * bf2f(u4.y);
      acc.z += w4_ * bf2f(u4.z); acc.w += w4_ * bf2f(u4.w);
      acc.x += w5 * bf2f(u5.x); acc.y += w5 * bf2f(u5.y);
      acc.z += w5 * bf2f(u5.z); acc.w += w5 * bf2f(u5.w);
      acc.x += w6 * bf2f(u6.x); acc.y += w6 * bf2f(u6.y);
      acc.z += w6 * bf2f(u6.z); acc.w += w6 * bf2f(u6.w);
      acc.x += w7 * bf2f(u7.x); acc.y += w7 * bf2f(u7.y);
      acc.z += w7 * bf2f(u7.z); acc.w += w7 * bf2f(u7.w);
    }
    for (; j < nc; j++) {
      int sj = srow[j];
      float ww = wrow[4 * j];
      ushort4 u = *(const ushort4*)(hbase + ((size_t)((uint)sj << 9)));
      wsum += ww;
      acc.x += ww * bf2f(u.x); acc.y += ww * bf2f(u.y);
      acc.z += ww * bf2f(u.z); acc.w += ww * bf2f(u.w);
    }
  }

  float inv = 1.0f / wsum;  // deg>=1 via self-loop
  float4 v = make_float4(acc.x * inv, acc.y * inv, acc.z * inv, acc.w * inv);

  if (LAYER == 1) {
    const float4 bv = *(const float4*)(bias + lane * 4);
    v.x = fmaxf(v.x + bv.x, 0.f);
    v.y = fmaxf(v.y + bv.y, 0.f);
    v.z = fmaxf(v.z + bv.z, 0.f);
    v.w = fmaxf(v.w + bv.w, 0.f);
    ushort4 h, l;
    h.x = f2bf(v.x); l.x = f2bf(v.x - bf2f(h.x));
    h.y = f2bf(v.y); l.y = f2bf(v.y - bf2f(h.y));
    h.z = f2bf(v.z); l.z = f2bf(v.z - bf2f(h.z));
    h.w = f2bf(v.w); l.w = f2bf(v.w - bf2f(h.w));
    const size_t o = (size_t)node * 256 + lane * 4;
    *(ushort4*)(out_h + o) = h;
    *(ushort4*)(out_l + o) = l;
  } else {
    // fused finale: head-mean + bias + relu + softmax(64)
    v.x += __shfl_xor(v.x, 16); v.y += __shfl_xor(v.y, 16);
    v.z += __shfl_xor(v.z, 16); v.w += __shfl_xor(v.w, 16);
    v.x += __shfl_xor(v.x, 32); v.y += __shfl_xor(v.y, 32);
    v.z += __shfl_xor(v.z, 32); v.w += __shfl_xor(v.w, 32);
    const int c4 = (lane & 15) * 4;
    const float4 bv = *(const float4*)(bias + c4);
    v.x = fmaxf(v.x * 0.25f + bv.x, 0.f);
    v.y = fmaxf(v.y * 0.25f + bv.y, 0.f);
    v.z = fmaxf(v.z * 0.25f + bv.z, 0.f);
    v.w = fmaxf(v.w * 0.25f + bv.w, 0.f);
    float mx = fmaxf(fmaxf(v.x, v.y), fmaxf(v.z, v.w));
    for (int off = 8; off >= 1; off >>= 1) mx = fmaxf(mx, __shfl_xor(mx, off));
    v.x = __expf(v.x - mx); v.y = __expf(v.y - mx);
    v.z = __expf(v.z - mx); v.w = __expf(v.w - mx);
    float sum = v.x + v.y + v.z + v.w;
    for (int off = 8; off >= 1; off >>= 1) sum += __shfl_xor(sum, off);
    float is = 1.0f / sum;
    v.x *= is; v.y *= is; v.z *= is; v.w *= is;
    if (lane < 16) *(float4*)(outp + (size_t)node * 64 + c4) = v;
  }
}

// ---------------------------------------------------------------------------

extern "C" void kernel_launch(void* const* d_in, const int* in_sizes, int n_in,
                              void* d_out, int out_size, void* d_ws, size_t ws_size,
                              hipStream_t stream) {
  const float* x   = (const float*)d_in[0];
  const int*   ei  = (const int*)d_in[1];
  const float* W1  = (const float*)d_in[2];
  const float* as1 = (const float*)d_in[3];
  const float* ad1 = (const float*)d_in[4];
  const float* b1  = (const float*)d_in[5];
  const float* W2  = (const float*)d_in[6];
  const float* as2 = (const float*)d_in[7];
  const float* ad2 = (const float*)d_in[8];
  const float* b2  = (const float*)d_in[9];
  float* out = (float*)d_out;

  const int N = in_sizes[0] / 128;
  const int E = in_sizes[1] / 2;
  const int* srcv = ei;
  const int* dstv = ei + E;

  // ---- workspace layout
  ushort* h1   = (ushort*)d_ws;                   // [N,256] bf16 (also h2)
  ushort* hb_h = h1 + (size_t)N * 256;            // [N,256] bf16
  ushort* hb_l = hb_h + (size_t)N * 256;          // [N,256] bf16
  ushort* w1th = hb_l + (size_t)N * 256;          // [256][128] x2
  ushort* w1tl = w1th + 256 * 128;
  ushort* w2th = w1tl + 256 * 128;                // [256][256] x2
  ushort* w2tl = w2th + 256 * 256;
  float*  zbuf = (float*)(w2tl + 256 * 256);      // a_s1,a_d1,a_s2,a_d2 [16N]
  float* a_s1 = zbuf;
  float* a_d1 = a_s1 + (size_t)N * 4;
  float* a_s2 = a_d1 + (size_t)N * 4;
  float* a_d2 = a_s2 + (size_t)N * 4;
  int* rowptr = (int*)(zbuf + (size_t)N * 16);    // [N+1] (+pad)
  int* cnt    = rowptr + (N + 4);                 // [N]      (memset region)
  int* bflag  = cnt + N;                          // [256]    (memset region)
  int* bsum   = bflag + 256;                      // [256]
  int* pe     = bsum + 256;                       // [E]  per-edge slot
  int* colx   = pe + E;                           // [E]

  const int nb = (N + 255) / 256;  // <=256 required by k_scan lookback
  const int eb = (E + 255) / 256;

  // XCD-aligned swizzled 1-D grid: 16 blocks per group of 8 row blocks
  const int nrb = (N + 127) / 128;
  const int gemm_blocks = ((nrb + 7) / 8) * 16;
  const int wb = (N + 3) / 4;  // one wave per node

  hipMemsetAsync(cnt, 0, ((size_t)N + 256) * 4, stream);  // cnt + bflag
  k_prep_hist<<<384 + eb, 256, 0, stream>>>(W1, W2, w1th, w1tl, w2th, w2tl,
                                            dstv, cnt, pe, E);
  k_scan<<<nb, 256, 0, stream>>>(cnt, rowptr, bsum, bflag, N, E);
  k_gemm1_scatter<<<gemm_blocks + eb, 256, 0, stream>>>(
      x, w1th, w1tl, h1, N, as1, ad1, a_s1, a_d1,
      srcv, dstv, rowptr, pe, colx, E, gemm_blocks);
  k_aggr<1><<<wb, 256, 0, stream>>>(h1, rowptr, colx, a_s1, a_d1, b1,
                                    hb_h, hb_l, nullptr, N);
  k_gemm2<<<gemm_blocks, 256, 0, stream>>>(hb_h, hb_l, w2th, w2tl, h1, N,
                                           as2, ad2, a_s2, a_d2);
  k_aggr<2><<<wb, 256, 0, stream>>>(h1, rowptr, colx, a_s2, a_d2, b2,
                                    nullptr, nullptr, out, N);
}

// Round 18
// 343.056 us; speedup vs baseline: 1.3392x; 1.0499x over previous
//
#include <hip/hip_runtime.h>

// ---------------------------------------------------------------------------
// 2-layer GAT (PyG GATConv), MI355X.
// R18 (from R17 = 360us best):
//   (1) hb (aggr1 output) stored PLAIN bf16 (was split h/l). Accuracy budget:
//       adds one ~0.4%-rel rounding like the existing h1/h2 roundings ->
//       predicted absmax ~2-2.5e-4 < 4.17e-4 threshold.
//       Payoff: gemm2 = 2 MFMA terms (Ah*Bh + Ah*Bl), A-fetch halved,
//       LDS 20.5->10.2KB (occupancy ~2x), aggr1 epilogue loses the split.
//   (2) aggr j-loop unroll back to 4 (R17's unroll-8 was neutral/negative:
//       66.5->67.8us, occ 71->62%).
//   Everything else frozen from R17.
// ---------------------------------------------------------------------------

typedef __attribute__((ext_vector_type(8))) short short8;
typedef __attribute__((ext_vector_type(4))) float f32x4;

static __device__ __forceinline__ ushort f2bf(float f) {  // RNE
  uint u = __float_as_uint(f);
  return (ushort)((u + 0x7FFFu + ((u >> 16) & 1u)) >> 16);
}
static __device__ __forceinline__ float bf2f(ushort s) {
  return __uint_as_float(((uint)s) << 16);
}
static __device__ __forceinline__ void split8(const float4& a, const float4& b,
                                              uint4& hh, uint4& ll) {
  ushort h0 = f2bf(a.x), h1 = f2bf(a.y), h2 = f2bf(a.z), h3 = f2bf(a.w);
  ushort h4 = f2bf(b.x), h5 = f2bf(b.y), h6 = f2bf(b.z), h7 = f2bf(b.w);
  hh.x = (uint)h0 | ((uint)h1 << 16); hh.y = (uint)h2 | ((uint)h3 << 16);
  hh.z = (uint)h4 | ((uint)h5 << 16); hh.w = (uint)h6 | ((uint)h7 << 16);
  ll.x = (uint)f2bf(a.x - bf2f(h0)) | ((uint)f2bf(a.y - bf2f(h1)) << 16);
  ll.y = (uint)f2bf(a.z - bf2f(h2)) | ((uint)f2bf(a.w - bf2f(h3)) << 16);
  ll.z = (uint)f2bf(b.x - bf2f(h4)) | ((uint)f2bf(b.y - bf2f(h5)) << 16);
  ll.w = (uint)f2bf(b.z - bf2f(h6)) | ((uint)f2bf(b.w - bf2f(h7)) << 16);
}

// ---------- fused weight-prep + dst histogram (+ per-edge slot pe) ---------
__global__ __launch_bounds__(256)
void k_prep_hist(const float* __restrict__ W1, const float* __restrict__ W2,
                 ushort* __restrict__ w1th, ushort* __restrict__ w1tl,
                 ushort* __restrict__ w2th, ushort* __restrict__ w2tl,
                 const int* __restrict__ dstv, int* __restrict__ cnt,
                 int* __restrict__ pe, int E) {
  const int b = blockIdx.x;
  if (b < 128) {  // W1 [128][256] -> [256][128] split
    int gid = b * 256 + threadIdx.x;
    int c = gid & 255, k = gid >> 8;
    float w = W1[(size_t)k * 256 + c];
    ushort h = f2bf(w);
    w1th[(size_t)c * 128 + k] = h;
    w1tl[(size_t)c * 128 + k] = f2bf(w - bf2f(h));
  } else if (b < 384) {  // W2 [256][256] -> [256][256] split
    int gid = (b - 128) * 256 + threadIdx.x;
    int c = gid & 255, k = gid >> 8;
    float w = W2[(size_t)k * 256 + c];
    ushort h = f2bf(w);
    w2th[(size_t)c * 256 + k] = h;
    w2tl[(size_t)c * 256 + k] = f2bf(w - bf2f(h));
  } else {  // histogram of dst; atomic return value = edge's slot
    int i = (b - 384) * 256 + threadIdx.x;
    if (i < E) pe[i] = atomicAdd(&cnt[dstv[i]], 1);
  }
}

// Single-pass exclusive scan with decoupled lookback (grid <= 256 blocks).
__global__ __launch_bounds__(256)
void k_scan(const int* __restrict__ cnt, int* __restrict__ rowptr,
            int* __restrict__ bsum, int* __restrict__ bflag, int N, int E) {
  __shared__ int sm[256];
  __shared__ int s_prev;
  const int b = blockIdx.x, tid = threadIdx.x;
  const int gid = b * 256 + tid;
  int v = (gid < N) ? cnt[gid] : 0;
  sm[tid] = v;
  __syncthreads();
  for (int off = 1; off < 256; off <<= 1) {
    int t = (tid >= off) ? sm[tid - off] : 0;
    __syncthreads();
    sm[tid] += t;
    __syncthreads();
  }
  if (tid == 255) {
    atomicExch(&bsum[b], sm[255]);
    __threadfence();
    atomicExch(&bflag[b], 1);
  }
  if (tid == 0) s_prev = 0;
  __syncthreads();
  if (tid < b) {
    while (atomicAdd(&bflag[tid], 0) == 0) {}
    atomicAdd(&s_prev, atomicAdd(&bsum[tid], 0));
  }
  __syncthreads();
  if (gid < N) rowptr[gid] = s_prev + sm[tid] - v;
  if (gid == 0) rowptr[N] = E;
}

// ----------------------------- MFMA GEMM body ------------------------------
// C[N,256] = A @ (Bh+Bl)[K,256], Bt stored [256][K].
// MODE=1: A fp32, split to bf16 h/l inline during LDS staging; 3 MFMA terms.
// MODE=0: A plain bf16; 2 MFMA terms (Ah*Bh + Ah*Bl); LDS holds Ah only.
// B fragments direct from global (L1/L2-hot panel).
// XCD-aligned swizzle: col-halves of a row block differ by 8 block ids.
template <int MODE>
static __device__ __forceinline__
void gemm_body(int bid, const void* __restrict__ Aany,
               const ushort* __restrict__ Bth, const ushort* __restrict__ Btl,
               ushort* __restrict__ hout, int Nrows, int K,
               const float* __restrict__ att_s, const float* __restrict__ att_d,
               float* __restrict__ a_s, float* __restrict__ a_d) {
  __shared__ ushort As_h[128][40];
  __shared__ ushort As_l[(MODE == 1) ? 128 : 1][40];

  const int nrb = (Nrows + 127) >> 7;
  const int rb = (bid >> 4) * 8 + (bid & 7);
  const int ch = (bid >> 3) & 1;
  if (rb >= nrb) return;
  const int row0 = rb * 128;
  const int col0 = ch * 128;

  const int t = threadIdx.x;
  const int lane = t & 63;
  const int w = t >> 6;
  const int wr = (w >> 1) * 64;
  const int wc = (w & 1) * 64;
  const int lrow = t >> 2;       // 0..63 staging row index
  const int kc = (t & 3) * 8;    // k-chunk within BK=32

  const float*  Af = (const float*)Aany;    // MODE=1
  const ushort* Ah = (const ushort*)Aany;   // MODE=0

  f32x4 acc[4][4] = {};

  float4 pf[2][2];
  uint4 pa_h[2];
  const uint4 z4 = make_uint4(0, 0, 0, 0);
#pragma unroll
  for (int p = 0; p < 2; p++) {
    int gr = row0 + p * 64 + lrow;
    if (MODE == 1) {
      if (gr < Nrows) {
        const float* ap = Af + (size_t)gr * K + kc;
        pf[p][0] = *(const float4*)(ap);
        pf[p][1] = *(const float4*)(ap + 4);
      } else {
        pf[p][0] = make_float4(0.f, 0.f, 0.f, 0.f);
        pf[p][1] = pf[p][0];
      }
    } else {
      if (gr < Nrows) pa_h[p] = *(const uint4*)(Ah + (size_t)gr * K + kc);
      else pa_h[p] = z4;
    }
  }

  const int fr = lane & 15;
  const int fq = lane >> 4;
  const ushort* bb_h = Bth + (size_t)(col0 + wc + fr) * K + fq * 8;
  const ushort* bb_l = Btl + (size_t)(col0 + wc + fr) * K + fq * 8;

  for (int k0 = 0; k0 < K; k0 += 32) {
#pragma unroll
    for (int p = 0; p < 2; p++) {
      if (MODE == 1) {
        uint4 hh, ll;
        split8(pf[p][0], pf[p][1], hh, ll);
        *(uint4*)(&As_h[p * 64 + lrow][kc]) = hh;
        *(uint4*)(&As_l[p * 64 + lrow][kc]) = ll;
      } else {
        *(uint4*)(&As_h[p * 64 + lrow][kc]) = pa_h[p];
      }
    }
    __syncthreads();

    if (k0 + 32 < K) {
#pragma unroll
      for (int p = 0; p < 2; p++) {
        int gr = row0 + p * 64 + lrow;
        if (MODE == 1) {
          if (gr < Nrows) {
            const float* ap = Af + (size_t)gr * K + k0 + 32 + kc;
            pf[p][0] = *(const float4*)(ap);
            pf[p][1] = *(const float4*)(ap + 4);
          } else {
            pf[p][0] = make_float4(0.f, 0.f, 0.f, 0.f);
            pf[p][1] = pf[p][0];
          }
        } else {
          if (gr < Nrows)
            pa_h[p] = *(const uint4*)(Ah + (size_t)gr * K + k0 + 32 + kc);
          else pa_h[p] = z4;
        }
      }
    }

    short8 fb_h[4], fb_l[4];
#pragma unroll
    for (int c = 0; c < 4; c++) {
      fb_h[c] = *(const short8*)(bb_h + (size_t)c * 16 * K + k0);
      fb_l[c] = *(const short8*)(bb_l + (size_t)c * 16 * K + k0);
    }
    short8 fa_h[4], fa_l[4];
#pragma unroll
    for (int r = 0; r < 4; r++) {
      fa_h[r] = *(const short8*)(&As_h[wr + r * 16 + fr][fq * 8]);
      if (MODE == 1)
        fa_l[r] = *(const short8*)(&As_l[wr + r * 16 + fr][fq * 8]);
    }
#pragma unroll
    for (int r = 0; r < 4; r++)
#pragma unroll
      for (int c = 0; c < 4; c++) {
        acc[r][c] = __builtin_amdgcn_mfma_f32_16x16x32_bf16(fa_h[r], fb_h[c], acc[r][c], 0, 0, 0);
        if (MODE == 1)
          acc[r][c] = __builtin_amdgcn_mfma_f32_16x16x32_bf16(fa_l[r], fb_h[c], acc[r][c], 0, 0, 0);
        acc[r][c] = __builtin_amdgcn_mfma_f32_16x16x32_bf16(fa_h[r], fb_l[c], acc[r][c], 0, 0, 0);
      }
    __syncthreads();
  }

  // ---- C write (bf16, direct — L2 absorbs the 2B scatter)
#pragma unroll
  for (int r = 0; r < 4; r++)
#pragma unroll
    for (int c = 0; c < 4; c++) {
      int colg = col0 + wc + c * 16 + fr;
#pragma unroll
      for (int reg = 0; reg < 4; reg++) {
        int gr = row0 + wr + r * 16 + fq * 4 + reg;
        if (gr < Nrows) hout[(size_t)gr * 256 + colg] = f2bf(acc[r][c][reg]);
      }
    }

  // ---- attention scores: wave's 64 cols = one head (wc 64-aligned)
  const int head = (col0 + wc) >> 6;
  float asv[4], adv[4];
#pragma unroll
  for (int c = 0; c < 4; c++) {
    asv[c] = att_s[col0 + wc + c * 16 + fr];
    adv[c] = att_d[col0 + wc + c * 16 + fr];
  }
#pragma unroll
  for (int r = 0; r < 4; r++)
#pragma unroll
    for (int reg = 0; reg < 4; reg++) {
      float ps = 0.f, pd = 0.f;
#pragma unroll
      for (int c = 0; c < 4; c++) {
        ps += acc[r][c][reg] * asv[c];
        pd += acc[r][c][reg] * adv[c];
      }
      ps += __shfl_xor(ps, 1); pd += __shfl_xor(pd, 1);
      ps += __shfl_xor(ps, 2); pd += __shfl_xor(pd, 2);
      ps += __shfl_xor(ps, 4); pd += __shfl_xor(pd, 4);
      ps += __shfl_xor(ps, 8); pd += __shfl_xor(pd, 8);
      if (fr == 0) {
        int gr = row0 + wr + r * 16 + fq * 4 + reg;
        if (gr < Nrows) {
          a_s[(size_t)gr * 4 + head] = ps;
          a_d[(size_t)gr * 4 + head] = pd;
        }
      }
    }
}

// ---- fused: gemm1 blocks first, NON-ATOMIC scatter blocks backfill --------
__global__ __launch_bounds__(256)
void k_gemm1_scatter(const float* __restrict__ x,
                     const ushort* __restrict__ Bth,
                     const ushort* __restrict__ Btl,
                     ushort* __restrict__ hout, int Nrows,
                     const float* __restrict__ att_s,
                     const float* __restrict__ att_d,
                     float* __restrict__ a_s, float* __restrict__ a_d,
                     const int* __restrict__ srcv, const int* __restrict__ dstv,
                     const int* __restrict__ rowptr, const int* __restrict__ pe,
                     int* __restrict__ col, int E, int gemm_blocks) {
  if ((int)blockIdx.x < gemm_blocks) {
    gemm_body<1>(blockIdx.x, x, Bth, Btl, hout, Nrows, 128,
                 att_s, att_d, a_s, a_d);
  } else {
    int i = ((int)blockIdx.x - gemm_blocks) * 256 + threadIdx.x;
    if (i < E) col[rowptr[dstv[i]] + pe[i]] = srcv[i];
  }
}

__global__ __launch_bounds__(256)
void k_gemm2(const ushort* __restrict__ Ah,
             const ushort* __restrict__ Bth, const ushort* __restrict__ Btl,
             ushort* __restrict__ hout, int Nrows,
             const float* __restrict__ att_s, const float* __restrict__ att_d,
             float* __restrict__ a_s, float* __restrict__ a_d) {
  gemm_body<0>(blockIdx.x, Ah, Bth, Btl, hout, Nrows, 256,
               att_s, att_d, a_s, a_d);
}

// ----------------------------- aggregation ---------------------------------
// ONE wave per node; lane owns channels [4*lane, 4*lane+3] (ushort4 gather),
// head = lane>>4. Chunk of 64 edges: lane gathers a_s[col] float4, computes
// all-head weights inline, stages (src, w[4]) in LDS. Denominator free.
// LAYER 1: relu(acc/den + bias) -> plain bf16 (out_h).
// LAYER 2: fused finale — head-mean + bias + relu + softmax(64) -> outp.
template <int LAYER>
__global__ __launch_bounds__(256)
void k_aggr(const ushort* __restrict__ hsrc, const int* __restrict__ rowptr,
            const int* __restrict__ col, const float* __restrict__ a_s,
            const float* __restrict__ a_d, const float* __restrict__ bias,
            ushort* __restrict__ out_h, float* __restrict__ outp, int N) {
  __shared__ int   s_sh[4][64];
  __shared__ float w_sh[4][256];
  const int wv = threadIdx.x >> 6;
  const int lane = threadIdx.x & 63;
  const int node = blockIdx.x * 4 + wv;
  if (node >= N) return;
  const int hd = lane >> 4;
  const int beg = rowptr[node], end = rowptr[node + 1];
  const float4 adst = *(const float4*)(a_d + (size_t)node * 4);

  float4 acc = make_float4(0.f, 0.f, 0.f, 0.f);
  float wsum = 0.f;
  const char* hbase = (const char*)(hsrc + lane * 4);

  for (int c0 = beg; c0 < end; c0 += 64) {
    int nc = min(64, end - c0);
    int s = 0;
    float4 w4 = make_float4(0.f, 0.f, 0.f, 0.f);
    if (lane < nc) {
      s = col[c0 + lane];
      float4 a = *(const float4*)(a_s + (size_t)s * 4);
      float e0 = a.x + adst.x; e0 = e0 > 0.f ? e0 : 0.2f * e0;
      float e1 = a.y + adst.y; e1 = e1 > 0.f ? e1 : 0.2f * e1;
      float e2 = a.z + adst.z; e2 = e2 > 0.f ? e2 : 0.2f * e2;
      float e3 = a.w + adst.w; e3 = e3 > 0.f ? e3 : 0.2f * e3;
      w4 = make_float4(__expf(e0), __expf(e1), __expf(e2), __expf(e3));
    }
    s_sh[wv][lane] = s;
    *(float4*)(&w_sh[wv][lane * 4]) = w4;
    asm volatile("s_waitcnt lgkmcnt(0)" ::: "memory");

    const float* wrow = &w_sh[wv][hd];
    const int*   srow = &s_sh[wv][0];
    int j = 0;
    for (; j + 4 <= nc; j += 4) {
      int sj0 = srow[j], sj1 = srow[j + 1], sj2 = srow[j + 2], sj3 = srow[j + 3];
      float w0 = wrow[4 * j],      w1 = wrow[4 * j + 4];
      float w2 = wrow[4 * j + 8],  w3 = wrow[4 * j + 12];
      ushort4 u0 = *(const ushort4*)(hbase + ((size_t)((uint)sj0 << 9)));
      ushort4 u1 = *(const ushort4*)(hbase + ((size_t)((uint)sj1 << 9)));
      ushort4 u2 = *(const ushort4*)(hbase + ((size_t)((uint)sj2 << 9)));
      ushort4 u3 = *(const ushort4*)(hbase + ((size_t)((uint)sj3 << 9)));
      wsum += w0 + w1 + w2 + w3;
      acc.x += w0 * bf2f(u0.x); acc.y += w0 * bf2f(u0.y);
      acc.z += w0 * bf2f(u0.z); acc.w += w0 * bf2f(u0.w);
      acc.x += w1 * bf2f(u1.x); acc.y += w1 * bf2f(u1.y);
      acc.z += w1 * bf2f(u1.z); acc.w += w1 * bf2f(u1.w);
      acc.x += w2 * bf2f(u2.x); acc.y += w2 * bf2f(u2.y);
      acc.z += w2 * bf2f(u2.z); acc.w += w2 * bf2f(u2.w);
      acc.x += w3 * bf2f(u3.x); acc.y += w3 * bf2f(u3.y);
      acc.z += w3 * bf2f(u3.z); acc.w += w3 * bf2f(u3.w);
    }
    for (; j < nc; j++) {
      int sj = srow[j];
      float ww = wrow[4 * j];
      ushort4 u = *(const ushort4*)(hbase + ((size_t)((uint)sj << 9)));
      wsum += ww;
      acc.x += ww * bf2f(u.x); acc.y += ww * bf2f(u.y);
      acc.z += ww * bf2f(u.z); acc.w += ww * bf2f(u.w);
    }
  }

  float inv = 1.0f / wsum;  // deg>=1 via self-loop
  float4 v = make_float4(acc.x * inv, acc.y * inv, acc.z * inv, acc.w * inv);

  if (LAYER == 1) {
    const float4 bv = *(const float4*)(bias + lane * 4);
    v.x = fmaxf(v.x + bv.x, 0.f);
    v.y = fmaxf(v.y + bv.y, 0.f);
    v.z = fmaxf(v.z + bv.z, 0.f);
    v.w = fmaxf(v.w + bv.w, 0.f);
    ushort4 h;
    h.x = f2bf(v.x); h.y = f2bf(v.y); h.z = f2bf(v.z); h.w = f2bf(v.w);
    *(ushort4*)(out_h + (size_t)node * 256 + lane * 4) = h;
  } else {
    // fused finale: head-mean + bias + relu + softmax(64)
    v.x += __shfl_xor(v.x, 16); v.y += __shfl_xor(v.y, 16);
    v.z += __shfl_xor(v.z, 16); v.w += __shfl_xor(v.w, 16);
    v.x += __shfl_xor(v.x, 32); v.y += __shfl_xor(v.y, 32);
    v.z += __shfl_xor(v.z, 32); v.w += __shfl_xor(v.w, 32);
    const int c4 = (lane & 15) * 4;
    const float4 bv = *(const float4*)(bias + c4);
    v.x = fmaxf(v.x * 0.25f + bv.x, 0.f);
    v.y = fmaxf(v.y * 0.25f + bv.y, 0.f);
    v.z = fmaxf(v.z * 0.25f + bv.z, 0.f);
    v.w = fmaxf(v.w * 0.25f + bv.w, 0.f);
    float mx = fmaxf(fmaxf(v.x, v.y), fmaxf(v.z, v.w));
    for (int off = 8; off >= 1; off >>= 1) mx = fmaxf(mx, __shfl_xor(mx, off));
    v.x = __expf(v.x - mx); v.y = __expf(v.y - mx);
    v.z = __expf(v.z - mx); v.w = __expf(v.w - mx);
    float sum = v.x + v.y + v.z + v.w;
    for (int off = 8; off >= 1; off >>= 1) sum += __shfl_xor(sum, off);
    float is = 1.0f / sum;
    v.x *= is; v.y *= is; v.z *= is; v.w *= is;
    if (lane < 16) *(float4*)(outp + (size_t)node * 64 + c4) = v;
  }
}

// ---------------------------------------------------------------------------

extern "C" void kernel_launch(void* const* d_in, const int* in_sizes, int n_in,
                              void* d_out, int out_size, void* d_ws, size_t ws_size,
                              hipStream_t stream) {
  const float* x   = (const float*)d_in[0];
  const int*   ei  = (const int*)d_in[1];
  const float* W1  = (const float*)d_in[2];
  const float* as1 = (const float*)d_in[3];
  const float* ad1 = (const float*)d_in[4];
  const float* b1  = (const float*)d_in[5];
  const float* W2  = (const float*)d_in[6];
  const float* as2 = (const float*)d_in[7];
  const float* ad2 = (const float*)d_in[8];
  const float* b2  = (const float*)d_in[9];
  float* out = (float*)d_out;

  const int N = in_sizes[0] / 128;
  const int E = in_sizes[1] / 2;
  const int* srcv = ei;
  const int* dstv = ei + E;

  // ---- workspace layout
  ushort* h1   = (ushort*)d_ws;                   // [N,256] bf16 (also h2)
  ushort* hb   = h1 + (size_t)N * 256;            // [N,256] bf16 (plain)
  ushort* w1th = hb + (size_t)N * 256;            // [256][128] x2
  ushort* w1tl = w1th + 256 * 128;
  ushort* w2th = w1tl + 256 * 128;                // [256][256] x2
  ushort* w2tl = w2th + 256 * 256;
  float*  zbuf = (float*)(w2tl + 256 * 256);      // a_s1,a_d1,a_s2,a_d2 [16N]
  float* a_s1 = zbuf;
  float* a_d1 = a_s1 + (size_t)N * 4;
  float* a_s2 = a_d1 + (size_t)N * 4;
  float* a_d2 = a_s2 + (size_t)N * 4;
  int* rowptr = (int*)(zbuf + (size_t)N * 16);    // [N+1] (+pad)
  int* cnt    = rowptr + (N + 4);                 // [N]      (memset region)
  int* bflag  = cnt + N;                          // [256]    (memset region)
  int* bsum   = bflag + 256;                      // [256]
  int* pe     = bsum + 256;                       // [E]  per-edge slot
  int* colx   = pe + E;                           // [E]

  const int nb = (N + 255) / 256;  // <=256 required by k_scan lookback
  const int eb = (E + 255) / 256;

  // XCD-aligned swizzled 1-D grid: 16 blocks per group of 8 row blocks
  const int nrb = (N + 127) / 128;
  const int gemm_blocks = ((nrb + 7) / 8) * 16;
  const int wb = (N + 3) / 4;  // one wave per node

  hipMemsetAsync(cnt, 0, ((size_t)N + 256) * 4, stream);  // cnt + bflag
  k_prep_hist<<<384 + eb, 256, 0, stream>>>(W1, W2, w1th, w1tl, w2th, w2tl,
                                            dstv, cnt, pe, E);
  k_scan<<<nb, 256, 0, stream>>>(cnt, rowptr, bsum, bflag, N, E);
  k_gemm1_scatter<<<gemm_blocks + eb, 256, 0, stream>>>(
      x, w1th, w1tl, h1, N, as1, ad1, a_s1, a_d1,
      srcv, dstv, rowptr, pe, colx, E, gemm_blocks);
  k_aggr<1><<<wb, 256, 0, stream>>>(h1, rowptr, colx, a_s1, a_d1, b1,
                                    hb, nullptr, N);
  k_gemm2<<<gemm_blocks, 256, 0, stream>>>(hb, w2th, w2tl, h1, N,
                                           as2, ad2, a_s2, a_d2);
  k_aggr<2><<<wb, 256, 0, stream>>>(h1, rowptr, colx, a_s2, a_d2, b2,
                                    nullptr, out, N);
}

// Round 19
// 317.040 us; speedup vs baseline: 1.4491x; 1.0821x over previous
//
#include <hip/hip_runtime.h>

// ---------------------------------------------------------------------------
// 2-layer GAT (PyG GATConv), MI355X.
// R19 (from R18 = 343us best):
//   h1 (layer-1 features, gathered by aggr1) stored FP8 e4m3: per-XCD
//   compulsory gather traffic halves (aggr1 runs exactly at
//   hbm_bytes/3.73TB/s — R18 evidence). fp8 noise (~3%/chan) is averaged by
//   deg-17 aggregation and the K=256 contraction in gemm2 before reaching
//   the output -> ~0.2% net, inside the 2% budget. Layer-2 path stays bf16.
//   Everything else frozen from R18.
// ---------------------------------------------------------------------------

typedef __attribute__((ext_vector_type(8))) short short8;
typedef __attribute__((ext_vector_type(4))) float f32x4;
typedef __attribute__((ext_vector_type(2))) float f32x2;

static __device__ __forceinline__ ushort f2bf(float f) {  // RNE
  uint u = __float_as_uint(f);
  return (ushort)((u + 0x7FFFu + ((u >> 16) & 1u)) >> 16);
}
static __device__ __forceinline__ float bf2f(ushort s) {
  return __uint_as_float(((uint)s) << 16);
}
static __device__ __forceinline__ unsigned char f2fp8(float f) {  // e4m3 (HW)
  int p = __builtin_amdgcn_cvt_pk_fp8_f32(f, f, 0, false);
  return (unsigned char)(p & 0xFF);
}
static __device__ __forceinline__ void split8(const float4& a, const float4& b,
                                              uint4& hh, uint4& ll) {
  ushort h0 = f2bf(a.x), h1 = f2bf(a.y), h2 = f2bf(a.z), h3 = f2bf(a.w);
  ushort h4 = f2bf(b.x), h5 = f2bf(b.y), h6 = f2bf(b.z), h7 = f2bf(b.w);
  hh.x = (uint)h0 | ((uint)h1 << 16); hh.y = (uint)h2 | ((uint)h3 << 16);
  hh.z = (uint)h4 | ((uint)h5 << 16); hh.w = (uint)h6 | ((uint)h7 << 16);
  ll.x = (uint)f2bf(a.x - bf2f(h0)) | ((uint)f2bf(a.y - bf2f(h1)) << 16);
  ll.y = (uint)f2bf(a.z - bf2f(h2)) | ((uint)f2bf(a.w - bf2f(h3)) << 16);
  ll.z = (uint)f2bf(b.x - bf2f(h4)) | ((uint)f2bf(b.y - bf2f(h5)) << 16);
  ll.w = (uint)f2bf(b.z - bf2f(h6)) | ((uint)f2bf(b.w - bf2f(h7)) << 16);
}

// ---------- fused weight-prep + dst histogram (+ per-edge slot pe) ---------
__global__ __launch_bounds__(256)
void k_prep_hist(const float* __restrict__ W1, const float* __restrict__ W2,
                 ushort* __restrict__ w1th, ushort* __restrict__ w1tl,
                 ushort* __restrict__ w2th, ushort* __restrict__ w2tl,
                 const int* __restrict__ dstv, int* __restrict__ cnt,
                 int* __restrict__ pe, int E) {
  const int b = blockIdx.x;
  if (b < 128) {  // W1 [128][256] -> [256][128] split
    int gid = b * 256 + threadIdx.x;
    int c = gid & 255, k = gid >> 8;
    float w = W1[(size_t)k * 256 + c];
    ushort h = f2bf(w);
    w1th[(size_t)c * 128 + k] = h;
    w1tl[(size_t)c * 128 + k] = f2bf(w - bf2f(h));
  } else if (b < 384) {  // W2 [256][256] -> [256][256] split
    int gid = (b - 128) * 256 + threadIdx.x;
    int c = gid & 255, k = gid >> 8;
    float w = W2[(size_t)k * 256 + c];
    ushort h = f2bf(w);
    w2th[(size_t)c * 256 + k] = h;
    w2tl[(size_t)c * 256 + k] = f2bf(w - bf2f(h));
  } else {  // histogram of dst; atomic return value = edge's slot
    int i = (b - 384) * 256 + threadIdx.x;
    if (i < E) pe[i] = atomicAdd(&cnt[dstv[i]], 1);
  }
}

// Single-pass exclusive scan with decoupled lookback (grid <= 256 blocks).
__global__ __launch_bounds__(256)
void k_scan(const int* __restrict__ cnt, int* __restrict__ rowptr,
            int* __restrict__ bsum, int* __restrict__ bflag, int N, int E) {
  __shared__ int sm[256];
  __shared__ int s_prev;
  const int b = blockIdx.x, tid = threadIdx.x;
  const int gid = b * 256 + tid;
  int v = (gid < N) ? cnt[gid] : 0;
  sm[tid] = v;
  __syncthreads();
  for (int off = 1; off < 256; off <<= 1) {
    int t = (tid >= off) ? sm[tid - off] : 0;
    __syncthreads();
    sm[tid] += t;
    __syncthreads();
  }
  if (tid == 255) {
    atomicExch(&bsum[b], sm[255]);
    __threadfence();
    atomicExch(&bflag[b], 1);
  }
  if (tid == 0) s_prev = 0;
  __syncthreads();
  if (tid < b) {
    while (atomicAdd(&bflag[tid], 0) == 0) {}
    atomicAdd(&s_prev, atomicAdd(&bsum[tid], 0));
  }
  __syncthreads();
  if (gid < N) rowptr[gid] = s_prev + sm[tid] - v;
  if (gid == 0) rowptr[N] = E;
}

// ----------------------------- MFMA GEMM body ------------------------------
// C[N,256] = A @ (Bh+Bl)[K,256], Bt stored [256][K].
// MODE=1: A fp32, split inline during LDS staging; 3 terms; C -> FP8 e4m3.
// MODE=0: A plain bf16; 2 terms (Ah*Bh + Ah*Bl); C -> bf16.
// B fragments direct from global (L1/L2-hot panel); LDS holds A only.
// XCD-aligned swizzle: col-halves of a row block differ by 8 block ids.
template <int MODE>
static __device__ __forceinline__
void gemm_body(int bid, const void* __restrict__ Aany,
               const ushort* __restrict__ Bth, const ushort* __restrict__ Btl,
               void* __restrict__ hout, int Nrows, int K,
               const float* __restrict__ att_s, const float* __restrict__ att_d,
               float* __restrict__ a_s, float* __restrict__ a_d) {
  __shared__ ushort As_h[128][40];
  __shared__ ushort As_l[(MODE == 1) ? 128 : 1][40];

  const int nrb = (Nrows + 127) >> 7;
  const int rb = (bid >> 4) * 8 + (bid & 7);
  const int ch = (bid >> 3) & 1;
  if (rb >= nrb) return;
  const int row0 = rb * 128;
  const int col0 = ch * 128;

  const int t = threadIdx.x;
  const int lane = t & 63;
  const int w = t >> 6;
  const int wr = (w >> 1) * 64;
  const int wc = (w & 1) * 64;
  const int lrow = t >> 2;       // 0..63 staging row index
  const int kc = (t & 3) * 8;    // k-chunk within BK=32

  const float*  Af = (const float*)Aany;    // MODE=1
  const ushort* Ah = (const ushort*)Aany;   // MODE=0

  f32x4 acc[4][4] = {};

  float4 pf[2][2];
  uint4 pa_h[2];
  const uint4 z4 = make_uint4(0, 0, 0, 0);
#pragma unroll
  for (int p = 0; p < 2; p++) {
    int gr = row0 + p * 64 + lrow;
    if (MODE == 1) {
      if (gr < Nrows) {
        const float* ap = Af + (size_t)gr * K + kc;
        pf[p][0] = *(const float4*)(ap);
        pf[p][1] = *(const float4*)(ap + 4);
      } else {
        pf[p][0] = make_float4(0.f, 0.f, 0.f, 0.f);
        pf[p][1] = pf[p][0];
      }
    } else {
      if (gr < Nrows) pa_h[p] = *(const uint4*)(Ah + (size_t)gr * K + kc);
      else pa_h[p] = z4;
    }
  }

  const int fr = lane & 15;
  const int fq = lane >> 4;
  const ushort* bb_h = Bth + (size_t)(col0 + wc + fr) * K + fq * 8;
  const ushort* bb_l = Btl + (size_t)(col0 + wc + fr) * K + fq * 8;

  for (int k0 = 0; k0 < K; k0 += 32) {
#pragma unroll
    for (int p = 0; p < 2; p++) {
      if (MODE == 1) {
        uint4 hh, ll;
        split8(pf[p][0], pf[p][1], hh, ll);
        *(uint4*)(&As_h[p * 64 + lrow][kc]) = hh;
        *(uint4*)(&As_l[p * 64 + lrow][kc]) = ll;
      } else {
        *(uint4*)(&As_h[p * 64 + lrow][kc]) = pa_h[p];
      }
    }
    __syncthreads();

    if (k0 + 32 < K) {
#pragma unroll
      for (int p = 0; p < 2; p++) {
        int gr = row0 + p * 64 + lrow;
        if (MODE == 1) {
          if (gr < Nrows) {
            const float* ap = Af + (size_t)gr * K + k0 + 32 + kc;
            pf[p][0] = *(const float4*)(ap);
            pf[p][1] = *(const float4*)(ap + 4);
          } else {
            pf[p][0] = make_float4(0.f, 0.f, 0.f, 0.f);
            pf[p][1] = pf[p][0];
          }
        } else {
          if (gr < Nrows)
            pa_h[p] = *(const uint4*)(Ah + (size_t)gr * K + k0 + 32 + kc);
          else pa_h[p] = z4;
        }
      }
    }

    short8 fb_h[4], fb_l[4];
#pragma unroll
    for (int c = 0; c < 4; c++) {
      fb_h[c] = *(const short8*)(bb_h + (size_t)c * 16 * K + k0);
      fb_l[c] = *(const short8*)(bb_l + (size_t)c * 16 * K + k0);
    }
    short8 fa_h[4], fa_l[4];
#pragma unroll
    for (int r = 0; r < 4; r++) {
      fa_h[r] = *(const short8*)(&As_h[wr + r * 16 + fr][fq * 8]);
      if (MODE == 1)
        fa_l[r] = *(const short8*)(&As_l[wr + r * 16 + fr][fq * 8]);
    }
#pragma unroll
    for (int r = 0; r < 4; r++)
#pragma unroll
      for (int c = 0; c < 4; c++) {
        acc[r][c] = __builtin_amdgcn_mfma_f32_16x16x32_bf16(fa_h[r], fb_h[c], acc[r][c], 0, 0, 0);
        if (MODE == 1)
          acc[r][c] = __builtin_amdgcn_mfma_f32_16x16x32_bf16(fa_l[r], fb_h[c], acc[r][c], 0, 0, 0);
        acc[r][c] = __builtin_amdgcn_mfma_f32_16x16x32_bf16(fa_h[r], fb_l[c], acc[r][c], 0, 0, 0);
      }
    __syncthreads();
  }

  // ---- C write (fp8 for layer-1, bf16 for layer-2; L2 absorbs scatter)
#pragma unroll
  for (int r = 0; r < 4; r++)
#pragma unroll
    for (int c = 0; c < 4; c++) {
      int colg = col0 + wc + c * 16 + fr;
#pragma unroll
      for (int reg = 0; reg < 4; reg++) {
        int gr = row0 + wr + r * 16 + fq * 4 + reg;
        if (gr < Nrows) {
          if (MODE == 1)
            ((unsigned char*)hout)[(size_t)gr * 256 + colg] = f2fp8(acc[r][c][reg]);
          else
            ((ushort*)hout)[(size_t)gr * 256 + colg] = f2bf(acc[r][c][reg]);
        }
      }
    }

  // ---- attention scores: wave's 64 cols = one head (wc 64-aligned)
  const int head = (col0 + wc) >> 6;
  float asv[4], adv[4];
#pragma unroll
  for (int c = 0; c < 4; c++) {
    asv[c] = att_s[col0 + wc + c * 16 + fr];
    adv[c] = att_d[col0 + wc + c * 16 + fr];
  }
#pragma unroll
  for (int r = 0; r < 4; r++)
#pragma unroll
    for (int reg = 0; reg < 4; reg++) {
      float ps = 0.f, pd = 0.f;
#pragma unroll
      for (int c = 0; c < 4; c++) {
        ps += acc[r][c][reg] * asv[c];
        pd += acc[r][c][reg] * adv[c];
      }
      ps += __shfl_xor(ps, 1); pd += __shfl_xor(pd, 1);
      ps += __shfl_xor(ps, 2); pd += __shfl_xor(pd, 2);
      ps += __shfl_xor(ps, 4); pd += __shfl_xor(pd, 4);
      ps += __shfl_xor(ps, 8); pd += __shfl_xor(pd, 8);
      if (fr == 0) {
        int gr = row0 + wr + r * 16 + fq * 4 + reg;
        if (gr < Nrows) {
          a_s[(size_t)gr * 4 + head] = ps;
          a_d[(size_t)gr * 4 + head] = pd;
        }
      }
    }
}

// ---- fused: gemm1 blocks first, NON-ATOMIC scatter blocks backfill --------
__global__ __launch_bounds__(256)
void k_gemm1_scatter(const float* __restrict__ x,
                     const ushort* __restrict__ Bth,
                     const ushort* __restrict__ Btl,
                     unsigned char* __restrict__ hout, int Nrows,
                     const float* __restrict__ att_s,
                     const float* __restrict__ att_d,
                     float* __restrict__ a_s, float* __restrict__ a_d,
                     const int* __restrict__ srcv, const int* __restrict__ dstv,
                     const int* __restrict__ rowptr, const int* __restrict__ pe,
                     int* __restrict__ col, int E, int gemm_blocks) {
  if ((int)blockIdx.x < gemm_blocks) {
    gemm_body<1>(blockIdx.x, x, Bth, Btl, hout, Nrows, 128,
                 att_s, att_d, a_s, a_d);
  } else {
    int i = ((int)blockIdx.x - gemm_blocks) * 256 + threadIdx.x;
    if (i < E) col[rowptr[dstv[i]] + pe[i]] = srcv[i];
  }
}

__global__ __launch_bounds__(256)
void k_gemm2(const ushort* __restrict__ Ah,
             const ushort* __restrict__ Bth, const ushort* __restrict__ Btl,
             ushort* __restrict__ hout, int Nrows,
             const float* __restrict__ att_s, const float* __restrict__ att_d,
             float* __restrict__ a_s, float* __restrict__ a_d) {
  gemm_body<0>(blockIdx.x, Ah, Bth, Btl, hout, Nrows, 256,
               att_s, att_d, a_s, a_d);
}

// ----------------------------- aggregation ---------------------------------
// ONE wave per node; lane owns channels [4*lane, 4*lane+3], head = lane>>4.
// LAYER 1: h is FP8 e4m3 (4 B/lane gather, HW cvt decode);
//          out = relu(acc/den + bias) -> plain bf16.
// LAYER 2: h is bf16 (8 B/lane); fused finale — head-mean + bias + relu +
//          softmax(64) -> outp.
template <int LAYER>
__global__ __launch_bounds__(256)
void k_aggr(const void* __restrict__ hsrc, const int* __restrict__ rowptr,
            const int* __restrict__ col, const float* __restrict__ a_s,
            const float* __restrict__ a_d, const float* __restrict__ bias,
            ushort* __restrict__ out_h, float* __restrict__ outp, int N) {
  __shared__ int   s_sh[4][64];
  __shared__ float w_sh[4][256];
  const int wv = threadIdx.x >> 6;
  const int lane = threadIdx.x & 63;
  const int node = blockIdx.x * 4 + wv;
  if (node >= N) return;
  const int hd = lane >> 4;
  const int beg = rowptr[node], end = rowptr[node + 1];
  const float4 adst = *(const float4*)(a_d + (size_t)node * 4);

  float4 acc = make_float4(0.f, 0.f, 0.f, 0.f);
  float wsum = 0.f;
  // LAYER 1: 1 B/ch (row stride 256 B); LAYER 2: 2 B/ch (row stride 512 B)
  const char* hbase = (LAYER == 1)
      ? ((const char*)hsrc + lane * 4)
      : ((const char*)hsrc + lane * 8);

  for (int c0 = beg; c0 < end; c0 += 64) {
    int nc = min(64, end - c0);
    int s = 0;
    float4 w4 = make_float4(0.f, 0.f, 0.f, 0.f);
    if (lane < nc) {
      s = col[c0 + lane];
      float4 a = *(const float4*)(a_s + (size_t)s * 4);
      float e0 = a.x + adst.x; e0 = e0 > 0.f ? e0 : 0.2f * e0;
      float e1 = a.y + adst.y; e1 = e1 > 0.f ? e1 : 0.2f * e1;
      float e2 = a.z + adst.z; e2 = e2 > 0.f ? e2 : 0.2f * e2;
      float e3 = a.w + adst.w; e3 = e3 > 0.f ? e3 : 0.2f * e3;
      w4 = make_float4(__expf(e0), __expf(e1), __expf(e2), __expf(e3));
    }
    s_sh[wv][lane] = s;
    *(float4*)(&w_sh[wv][lane * 4]) = w4;
    asm volatile("s_waitcnt lgkmcnt(0)" ::: "memory");

    const float* wrow = &w_sh[wv][hd];
    const int*   srow = &s_sh[wv][0];
    int j = 0;
    for (; j + 4 <= nc; j += 4) {
      int sj0 = srow[j], sj1 = srow[j + 1], sj2 = srow[j + 2], sj3 = srow[j + 3];
      float w0 = wrow[4 * j],      w1 = wrow[4 * j + 4];
      float w2 = wrow[4 * j + 8],  w3 = wrow[4 * j + 12];
      if (LAYER == 1) {
        uint p0 = *(const uint*)(hbase + ((size_t)((uint)sj0 << 8)));
        uint p1 = *(const uint*)(hbase + ((size_t)((uint)sj1 << 8)));
        uint p2 = *(const uint*)(hbase + ((size_t)((uint)sj2 << 8)));
        uint p3 = *(const uint*)(hbase + ((size_t)((uint)sj3 << 8)));
        f32x2 l0 = __builtin_amdgcn_cvt_pk_f32_fp8(p0, false);
        f32x2 h0 = __builtin_amdgcn_cvt_pk_f32_fp8(p0, true);
        f32x2 l1 = __builtin_amdgcn_cvt_pk_f32_fp8(p1, false);
        f32x2 h1 = __builtin_amdgcn_cvt_pk_f32_fp8(p1, true);
        f32x2 l2 = __builtin_amdgcn_cvt_pk_f32_fp8(p2, false);
        f32x2 h2 = __builtin_amdgcn_cvt_pk_f32_fp8(p2, true);
        f32x2 l3 = __builtin_amdgcn_cvt_pk_f32_fp8(p3, false);
        f32x2 h3 = __builtin_amdgcn_cvt_pk_f32_fp8(p3, true);
        wsum += w0 + w1 + w2 + w3;
        acc.x += w0 * l0.x; acc.y += w0 * l0.y; acc.z += w0 * h0.x; acc.w += w0 * h0.y;
        acc.x += w1 * l1.x; acc.y += w1 * l1.y; acc.z += w1 * h1.x; acc.w += w1 * h1.y;
        acc.x += w2 * l2.x; acc.y += w2 * l2.y; acc.z += w2 * h2.x; acc.w += w2 * h2.y;
        acc.x += w3 * l3.x; acc.y += w3 * l3.y; acc.z += w3 * h3.x; acc.w += w3 * h3.y;
      } else {
        ushort4 u0 = *(const ushort4*)(hbase + ((size_t)((uint)sj0 << 9)));
        ushort4 u1 = *(const ushort4*)(hbase + ((size_t)((uint)sj1 << 9)));
        ushort4 u2 = *(const ushort4*)(hbase + ((size_t)((uint)sj2 << 9)));
        ushort4 u3 = *(const ushort4*)(hbase + ((size_t)((uint)sj3 << 9)));
        wsum += w0 + w1 + w2 + w3;
        acc.x += w0 * bf2f(u0.x); acc.y += w0 * bf2f(u0.y);
        acc.z += w0 * bf2f(u0.z); acc.w += w0 * bf2f(u0.w);
        acc.x += w1 * bf2f(u1.x); acc.y += w1 * bf2f(u1.y);
        acc.z += w1 * bf2f(u1.z); acc.w += w1 * bf2f(u1.w);
        acc.x += w2 * bf2f(u2.x); acc.y += w2 * bf2f(u2.y);
        acc.z += w2 * bf2f(u2.z); acc.w += w2 * bf2f(u2.w);
        acc.x += w3 * bf2f(u3.x); acc.y += w3 * bf2f(u3.y);
        acc.z += w3 * bf2f(u3.z); acc.w += w3 * bf2f(u3.w);
      }
    }
    for (; j < nc; j++) {
      int sj = srow[j];
      float ww = wrow[4 * j];
      wsum += ww;
      if (LAYER == 1) {
        uint p = *(const uint*)(hbase + ((size_t)((uint)sj << 8)));
        f32x2 lo = __builtin_amdgcn_cvt_pk_f32_fp8(p, false);
        f32x2 hi = __builtin_amdgcn_cvt_pk_f32_fp8(p, true);
        acc.x += ww * lo.x; acc.y += ww * lo.y;
        acc.z += ww * hi.x; acc.w += ww * hi.y;
      } else {
        ushort4 u = *(const ushort4*)(hbase + ((size_t)((uint)sj << 9)));
        acc.x += ww * bf2f(u.x); acc.y += ww * bf2f(u.y);
        acc.z += ww * bf2f(u.z); acc.w += ww * bf2f(u.w);
      }
    }
  }

  float inv = 1.0f / wsum;  // deg>=1 via self-loop
  float4 v = make_float4(acc.x * inv, acc.y * inv, acc.z * inv, acc.w * inv);

  if (LAYER == 1) {
    const float4 bv = *(const float4*)(bias + lane * 4);
    v.x = fmaxf(v.x + bv.x, 0.f);
    v.y = fmaxf(v.y + bv.y, 0.f);
    v.z = fmaxf(v.z + bv.z, 0.f);
    v.w = fmaxf(v.w + bv.w, 0.f);
    ushort4 h;
    h.x = f2bf(v.x); h.y = f2bf(v.y); h.z = f2bf(v.z); h.w = f2bf(v.w);
    *(ushort4*)(out_h + (size_t)node * 256 + lane * 4) = h;
  } else {
    // fused finale: head-mean + bias + relu + softmax(64)
    v.x += __shfl_xor(v.x, 16); v.y += __shfl_xor(v.y, 16);
    v.z += __shfl_xor(v.z, 16); v.w += __shfl_xor(v.w, 16);
    v.x += __shfl_xor(v.x, 32); v.y += __shfl_xor(v.y, 32);
    v.z += __shfl_xor(v.z, 32); v.w += __shfl_xor(v.w, 32);
    const int c4 = (lane & 15) * 4;
    const float4 bv = *(const float4*)(bias + c4);
    v.x = fmaxf(v.x * 0.25f + bv.x, 0.f);
    v.y = fmaxf(v.y * 0.25f + bv.y, 0.f);
    v.z = fmaxf(v.z * 0.25f + bv.z, 0.f);
    v.w = fmaxf(v.w * 0.25f + bv.w, 0.f);
    float mx = fmaxf(fmaxf(v.x, v.y), fmaxf(v.z, v.w));
    for (int off = 8; off >= 1; off >>= 1) mx = fmaxf(mx, __shfl_xor(mx, off));
    v.x = __expf(v.x - mx); v.y = __expf(v.y - mx);
    v.z = __expf(v.z - mx); v.w = __expf(v.w - mx);
    float sum = v.x + v.y + v.z + v.w;
    for (int off = 8; off >= 1; off >>= 1) sum += __shfl_xor(sum, off);
    float is = 1.0f / sum;
    v.x *= is; v.y *= is; v.z *= is; v.w *= is;
    if (lane < 16) *(float4*)(outp + (size_t)node * 64 + c4) = v;
  }
}

// ---------------------------------------------------------------------------

extern "C" void kernel_launch(void* const* d_in, const int* in_sizes, int n_in,
                              void* d_out, int out_size, void* d_ws, size_t ws_size,
                              hipStream_t stream) {
  const float* x   = (const float*)d_in[0];
  const int*   ei  = (const int*)d_in[1];
  const float* W1  = (const float*)d_in[2];
  const float* as1 = (const float*)d_in[3];
  const float* ad1 = (const float*)d_in[4];
  const float* b1  = (const float*)d_in[5];
  const float* W2  = (const float*)d_in[6];
  const float* as2 = (const float*)d_in[7];
  const float* ad2 = (const float*)d_in[8];
  const float* b2  = (const float*)d_in[9];
  float* out = (float*)d_out;

  const int N = in_sizes[0] / 128;
  const int E = in_sizes[1] / 2;
  const int* srcv = ei;
  const int* dstv = ei + E;

  // ---- workspace layout
  unsigned char* h8 = (unsigned char*)d_ws;       // [N,256] fp8 (layer-1 h)
  ushort* h2buf = (ushort*)d_ws;                  // [N,256] bf16 (layer-2 h,
                                                  //  reuses same region)
  ushort* hb   = (ushort*)d_ws + (size_t)N * 256; // [N,256] bf16 (aggr1 out)
  ushort* w1th = hb + (size_t)N * 256;            // [256][128] x2
  ushort* w1tl = w1th + 256 * 128;
  ushort* w2th = w1tl + 256 * 128;                // [256][256] x2
  ushort* w2tl = w2th + 256 * 256;
  float*  zbuf = (float*)(w2tl + 256 * 256);      // a_s1,a_d1,a_s2,a_d2 [16N]
  float* a_s1 = zbuf;
  float* a_d1 = a_s1 + (size_t)N * 4;
  float* a_s2 = a_d1 + (size_t)N * 4;
  float* a_d2 = a_s2 + (size_t)N * 4;
  int* rowptr = (int*)(zbuf + (size_t)N * 16);    // [N+1] (+pad)
  int* cnt    = rowptr + (N + 4);                 // [N]      (memset region)
  int* bflag  = cnt + N;                          // [256]    (memset region)
  int* bsum   = bflag + 256;                      // [256]
  int* pe     = bsum + 256;                       // [E]  per-edge slot
  int* colx   = pe + E;                           // [E]

  const int nb = (N + 255) / 256;  // <=256 required by k_scan lookback
  const int eb = (E + 255) / 256;

  // XCD-aligned swizzled 1-D grid: 16 blocks per group of 8 row blocks
  const int nrb = (N + 127) / 128;
  const int gemm_blocks = ((nrb + 7) / 8) * 16;
  const int wb = (N + 3) / 4;  // one wave per node

  hipMemsetAsync(cnt, 0, ((size_t)N + 256) * 4, stream);  // cnt + bflag
  k_prep_hist<<<384 + eb, 256, 0, stream>>>(W1, W2, w1th, w1tl, w2th, w2tl,
                                            dstv, cnt, pe, E);
  k_scan<<<nb, 256, 0, stream>>>(cnt, rowptr, bsum, bflag, N, E);
  k_gemm1_scatter<<<gemm_blocks + eb, 256, 0, stream>>>(
      x, w1th, w1tl, h8, N, as1, ad1, a_s1, a_d1,
      srcv, dstv, rowptr, pe, colx, E, gemm_blocks);
  k_aggr<1><<<wb, 256, 0, stream>>>(h8, rowptr, colx, a_s1, a_d1, b1,
                                    hb, nullptr, N);
  k_gemm2<<<gemm_blocks, 256, 0, stream>>>(hb, w2th, w2tl, h2buf, N,
                                           as2, ad2, a_s2, a_d2);
  k_aggr<2><<<wb, 256, 0, stream>>>(h2buf, rowptr, colx, a_s2, a_d2, b2,
                                    nullptr, out, N);
}

// Round 20
// 295.594 us; speedup vs baseline: 1.5542x; 1.0726x over previous
//
#include <hip/hip_runtime.h>

// ---------------------------------------------------------------------------
// 2-layer GAT (PyG GATConv), MI355X.
// R20 (from R19 = 317us best):
//   h2 (layer-2 features) ALSO stored FP8 e4m3 — symmetric to R19's h1 move.
//   Evidence: absmax has been pinned at the fp32-vs-np noise floor (1.22e-4)
//   through every bf16/fp8 change; the final softmax compresses upstream
//   relative error (~1.5% fp8 noise -> ~1-2e-4 in output space after deg-17
//   averaging, head-mean, and the softmax Jacobian). aggr2's 206MB @3.57TB/s
//   wall halves. Both aggr layers now share one fp8 gather path.
//   Everything else frozen from R19.
// ---------------------------------------------------------------------------

typedef __attribute__((ext_vector_type(8))) short short8;
typedef __attribute__((ext_vector_type(4))) float f32x4;
typedef __attribute__((ext_vector_type(2))) float f32x2;

static __device__ __forceinline__ ushort f2bf(float f) {  // RNE
  uint u = __float_as_uint(f);
  return (ushort)((u + 0x7FFFu + ((u >> 16) & 1u)) >> 16);
}
static __device__ __forceinline__ float bf2f(ushort s) {
  return __uint_as_float(((uint)s) << 16);
}
static __device__ __forceinline__ unsigned char f2fp8(float f) {  // e4m3 (HW)
  int p = __builtin_amdgcn_cvt_pk_fp8_f32(f, f, 0, false);
  return (unsigned char)(p & 0xFF);
}
static __device__ __forceinline__ void split8(const float4& a, const float4& b,
                                              uint4& hh, uint4& ll) {
  ushort h0 = f2bf(a.x), h1 = f2bf(a.y), h2 = f2bf(a.z), h3 = f2bf(a.w);
  ushort h4 = f2bf(b.x), h5 = f2bf(b.y), h6 = f2bf(b.z), h7 = f2bf(b.w);
  hh.x = (uint)h0 | ((uint)h1 << 16); hh.y = (uint)h2 | ((uint)h3 << 16);
  hh.z = (uint)h4 | ((uint)h5 << 16); hh.w = (uint)h6 | ((uint)h7 << 16);
  ll.x = (uint)f2bf(a.x - bf2f(h0)) | ((uint)f2bf(a.y - bf2f(h1)) << 16);
  ll.y = (uint)f2bf(a.z - bf2f(h2)) | ((uint)f2bf(a.w - bf2f(h3)) << 16);
  ll.z = (uint)f2bf(b.x - bf2f(h4)) | ((uint)f2bf(b.y - bf2f(h5)) << 16);
  ll.w = (uint)f2bf(b.z - bf2f(h6)) | ((uint)f2bf(b.w - bf2f(h7)) << 16);
}

// ---------- fused weight-prep + dst histogram (+ per-edge slot pe) ---------
__global__ __launch_bounds__(256)
void k_prep_hist(const float* __restrict__ W1, const float* __restrict__ W2,
                 ushort* __restrict__ w1th, ushort* __restrict__ w1tl,
                 ushort* __restrict__ w2th, ushort* __restrict__ w2tl,
                 const int* __restrict__ dstv, int* __restrict__ cnt,
                 int* __restrict__ pe, int E) {
  const int b = blockIdx.x;
  if (b < 128) {  // W1 [128][256] -> [256][128] split
    int gid = b * 256 + threadIdx.x;
    int c = gid & 255, k = gid >> 8;
    float w = W1[(size_t)k * 256 + c];
    ushort h = f2bf(w);
    w1th[(size_t)c * 128 + k] = h;
    w1tl[(size_t)c * 128 + k] = f2bf(w - bf2f(h));
  } else if (b < 384) {  // W2 [256][256] -> [256][256] split
    int gid = (b - 128) * 256 + threadIdx.x;
    int c = gid & 255, k = gid >> 8;
    float w = W2[(size_t)k * 256 + c];
    ushort h = f2bf(w);
    w2th[(size_t)c * 256 + k] = h;
    w2tl[(size_t)c * 256 + k] = f2bf(w - bf2f(h));
  } else {  // histogram of dst; atomic return value = edge's slot
    int i = (b - 384) * 256 + threadIdx.x;
    if (i < E) pe[i] = atomicAdd(&cnt[dstv[i]], 1);
  }
}

// Single-pass exclusive scan with decoupled lookback (grid <= 256 blocks).
__global__ __launch_bounds__(256)
void k_scan(const int* __restrict__ cnt, int* __restrict__ rowptr,
            int* __restrict__ bsum, int* __restrict__ bflag, int N, int E) {
  __shared__ int sm[256];
  __shared__ int s_prev;
  const int b = blockIdx.x, tid = threadIdx.x;
  const int gid = b * 256 + tid;
  int v = (gid < N) ? cnt[gid] : 0;
  sm[tid] = v;
  __syncthreads();
  for (int off = 1; off < 256; off <<= 1) {
    int t = (tid >= off) ? sm[tid - off] : 0;
    __syncthreads();
    sm[tid] += t;
    __syncthreads();
  }
  if (tid == 255) {
    atomicExch(&bsum[b], sm[255]);
    __threadfence();
    atomicExch(&bflag[b], 1);
  }
  if (tid == 0) s_prev = 0;
  __syncthreads();
  if (tid < b) {
    while (atomicAdd(&bflag[tid], 0) == 0) {}
    atomicAdd(&s_prev, atomicAdd(&bsum[tid], 0));
  }
  __syncthreads();
  if (gid < N) rowptr[gid] = s_prev + sm[tid] - v;
  if (gid == 0) rowptr[N] = E;
}

// ----------------------------- MFMA GEMM body ------------------------------
// C[N,256] = A @ (Bh+Bl)[K,256], Bt stored [256][K]. C emitted FP8 e4m3.
// MODE=1: A fp32, split inline during LDS staging; 3 MFMA terms.
// MODE=0: A plain bf16; 2 terms (Ah*Bh + Ah*Bl); LDS holds Ah only.
// B fragments direct from global (L1/L2-hot panel).
// XCD-aligned swizzle: col-halves of a row block differ by 8 block ids.
template <int MODE>
static __device__ __forceinline__
void gemm_body(int bid, const void* __restrict__ Aany,
               const ushort* __restrict__ Bth, const ushort* __restrict__ Btl,
               unsigned char* __restrict__ hout, int Nrows, int K,
               const float* __restrict__ att_s, const float* __restrict__ att_d,
               float* __restrict__ a_s, float* __restrict__ a_d) {
  __shared__ ushort As_h[128][40];
  __shared__ ushort As_l[(MODE == 1) ? 128 : 1][40];

  const int nrb = (Nrows + 127) >> 7;
  const int rb = (bid >> 4) * 8 + (bid & 7);
  const int ch = (bid >> 3) & 1;
  if (rb >= nrb) return;
  const int row0 = rb * 128;
  const int col0 = ch * 128;

  const int t = threadIdx.x;
  const int lane = t & 63;
  const int w = t >> 6;
  const int wr = (w >> 1) * 64;
  const int wc = (w & 1) * 64;
  const int lrow = t >> 2;       // 0..63 staging row index
  const int kc = (t & 3) * 8;    // k-chunk within BK=32

  const float*  Af = (const float*)Aany;    // MODE=1
  const ushort* Ah = (const ushort*)Aany;   // MODE=0

  f32x4 acc[4][4] = {};

  float4 pf[2][2];
  uint4 pa_h[2];
  const uint4 z4 = make_uint4(0, 0, 0, 0);
#pragma unroll
  for (int p = 0; p < 2; p++) {
    int gr = row0 + p * 64 + lrow;
    if (MODE == 1) {
      if (gr < Nrows) {
        const float* ap = Af + (size_t)gr * K + kc;
        pf[p][0] = *(const float4*)(ap);
        pf[p][1] = *(const float4*)(ap + 4);
      } else {
        pf[p][0] = make_float4(0.f, 0.f, 0.f, 0.f);
        pf[p][1] = pf[p][0];
      }
    } else {
      if (gr < Nrows) pa_h[p] = *(const uint4*)(Ah + (size_t)gr * K + kc);
      else pa_h[p] = z4;
    }
  }

  const int fr = lane & 15;
  const int fq = lane >> 4;
  const ushort* bb_h = Bth + (size_t)(col0 + wc + fr) * K + fq * 8;
  const ushort* bb_l = Btl + (size_t)(col0 + wc + fr) * K + fq * 8;

  for (int k0 = 0; k0 < K; k0 += 32) {
#pragma unroll
    for (int p = 0; p < 2; p++) {
      if (MODE == 1) {
        uint4 hh, ll;
        split8(pf[p][0], pf[p][1], hh, ll);
        *(uint4*)(&As_h[p * 64 + lrow][kc]) = hh;
        *(uint4*)(&As_l[p * 64 + lrow][kc]) = ll;
      } else {
        *(uint4*)(&As_h[p * 64 + lrow][kc]) = pa_h[p];
      }
    }
    __syncthreads();

    if (k0 + 32 < K) {
#pragma unroll
      for (int p = 0; p < 2; p++) {
        int gr = row0 + p * 64 + lrow;
        if (MODE == 1) {
          if (gr < Nrows) {
            const float* ap = Af + (size_t)gr * K + k0 + 32 + kc;
            pf[p][0] = *(const float4*)(ap);
            pf[p][1] = *(const float4*)(ap + 4);
          } else {
            pf[p][0] = make_float4(0.f, 0.f, 0.f, 0.f);
            pf[p][1] = pf[p][0];
          }
        } else {
          if (gr < Nrows)
            pa_h[p] = *(const uint4*)(Ah + (size_t)gr * K + k0 + 32 + kc);
          else pa_h[p] = z4;
        }
      }
    }

    short8 fb_h[4], fb_l[4];
#pragma unroll
    for (int c = 0; c < 4; c++) {
      fb_h[c] = *(const short8*)(bb_h + (size_t)c * 16 * K + k0);
      fb_l[c] = *(const short8*)(bb_l + (size_t)c * 16 * K + k0);
    }
    short8 fa_h[4], fa_l[4];
#pragma unroll
    for (int r = 0; r < 4; r++) {
      fa_h[r] = *(const short8*)(&As_h[wr + r * 16 + fr][fq * 8]);
      if (MODE == 1)
        fa_l[r] = *(const short8*)(&As_l[wr + r * 16 + fr][fq * 8]);
    }
#pragma unroll
    for (int r = 0; r < 4; r++)
#pragma unroll
      for (int c = 0; c < 4; c++) {
        acc[r][c] = __builtin_amdgcn_mfma_f32_16x16x32_bf16(fa_h[r], fb_h[c], acc[r][c], 0, 0, 0);
        if (MODE == 1)
          acc[r][c] = __builtin_amdgcn_mfma_f32_16x16x32_bf16(fa_l[r], fb_h[c], acc[r][c], 0, 0, 0);
        acc[r][c] = __builtin_amdgcn_mfma_f32_16x16x32_bf16(fa_h[r], fb_l[c], acc[r][c], 0, 0, 0);
      }
    __syncthreads();
  }

  // ---- C write (fp8 e4m3; L2 absorbs the 1B scatter)
#pragma unroll
  for (int r = 0; r < 4; r++)
#pragma unroll
    for (int c = 0; c < 4; c++) {
      int colg = col0 + wc + c * 16 + fr;
#pragma unroll
      for (int reg = 0; reg < 4; reg++) {
        int gr = row0 + wr + r * 16 + fq * 4 + reg;
        if (gr < Nrows)
          hout[(size_t)gr * 256 + colg] = f2fp8(acc[r][c][reg]);
      }
    }

  // ---- attention scores: wave's 64 cols = one head (wc 64-aligned)
  const int head = (col0 + wc) >> 6;
  float asv[4], adv[4];
#pragma unroll
  for (int c = 0; c < 4; c++) {
    asv[c] = att_s[col0 + wc + c * 16 + fr];
    adv[c] = att_d[col0 + wc + c * 16 + fr];
  }
#pragma unroll
  for (int r = 0; r < 4; r++)
#pragma unroll
    for (int reg = 0; reg < 4; reg++) {
      float ps = 0.f, pd = 0.f;
#pragma unroll
      for (int c = 0; c < 4; c++) {
        ps += acc[r][c][reg] * asv[c];
        pd += acc[r][c][reg] * adv[c];
      }
      ps += __shfl_xor(ps, 1); pd += __shfl_xor(pd, 1);
      ps += __shfl_xor(ps, 2); pd += __shfl_xor(pd, 2);
      ps += __shfl_xor(ps, 4); pd += __shfl_xor(pd, 4);
      ps += __shfl_xor(ps, 8); pd += __shfl_xor(pd, 8);
      if (fr == 0) {
        int gr = row0 + wr + r * 16 + fq * 4 + reg;
        if (gr < Nrows) {
          a_s[(size_t)gr * 4 + head] = ps;
          a_d[(size_t)gr * 4 + head] = pd;
        }
      }
    }
}

// ---- fused: gemm1 blocks first, NON-ATOMIC scatter blocks backfill --------
__global__ __launch_bounds__(256)
void k_gemm1_scatter(const float* __restrict__ x,
                     const ushort* __restrict__ Bth,
                     const ushort* __restrict__ Btl,
                     unsigned char* __restrict__ hout, int Nrows,
                     const float* __restrict__ att_s,
                     const float* __restrict__ att_d,
                     float* __restrict__ a_s, float* __restrict__ a_d,
                     const int* __restrict__ srcv, const int* __restrict__ dstv,
                     const int* __restrict__ rowptr, const int* __restrict__ pe,
                     int* __restrict__ col, int E, int gemm_blocks) {
  if ((int)blockIdx.x < gemm_blocks) {
    gemm_body<1>(blockIdx.x, x, Bth, Btl, hout, Nrows, 128,
                 att_s, att_d, a_s, a_d);
  } else {
    int i = ((int)blockIdx.x - gemm_blocks) * 256 + threadIdx.x;
    if (i < E) col[rowptr[dstv[i]] + pe[i]] = srcv[i];
  }
}

__global__ __launch_bounds__(256)
void k_gemm2(const ushort* __restrict__ Ah,
             const ushort* __restrict__ Bth, const ushort* __restrict__ Btl,
             unsigned char* __restrict__ hout, int Nrows,
             const float* __restrict__ att_s, const float* __restrict__ att_d,
             float* __restrict__ a_s, float* __restrict__ a_d) {
  gemm_body<0>(blockIdx.x, Ah, Bth, Btl, hout, Nrows, 256,
               att_s, att_d, a_s, a_d);
}

// ----------------------------- aggregation ---------------------------------
// ONE wave per node; lane owns channels [4*lane, 4*lane+3], head = lane>>4.
// h is FP8 e4m3 for BOTH layers: 4 B/lane gather (256 B/edge), HW cvt decode.
// LAYER 1: relu(acc/den + bias) -> plain bf16.
// LAYER 2: fused finale — head-mean + bias + relu + softmax(64) -> outp.
template <int LAYER>
__global__ __launch_bounds__(256)
void k_aggr(const unsigned char* __restrict__ hsrc,
            const int* __restrict__ rowptr, const int* __restrict__ col,
            const float* __restrict__ a_s, const float* __restrict__ a_d,
            const float* __restrict__ bias,
            ushort* __restrict__ out_h, float* __restrict__ outp, int N) {
  __shared__ int   s_sh[4][64];
  __shared__ float w_sh[4][256];
  const int wv = threadIdx.x >> 6;
  const int lane = threadIdx.x & 63;
  const int node = blockIdx.x * 4 + wv;
  if (node >= N) return;
  const int hd = lane >> 4;
  const int beg = rowptr[node], end = rowptr[node + 1];
  const float4 adst = *(const float4*)(a_d + (size_t)node * 4);

  float4 acc = make_float4(0.f, 0.f, 0.f, 0.f);
  float wsum = 0.f;
  const char* hbase = (const char*)hsrc + lane * 4;  // 256 B row stride

  for (int c0 = beg; c0 < end; c0 += 64) {
    int nc = min(64, end - c0);
    int s = 0;
    float4 w4 = make_float4(0.f, 0.f, 0.f, 0.f);
    if (lane < nc) {
      s = col[c0 + lane];
      float4 a = *(const float4*)(a_s + (size_t)s * 4);
      float e0 = a.x + adst.x; e0 = e0 > 0.f ? e0 : 0.2f * e0;
      float e1 = a.y + adst.y; e1 = e1 > 0.f ? e1 : 0.2f * e1;
      float e2 = a.z + adst.z; e2 = e2 > 0.f ? e2 : 0.2f * e2;
      float e3 = a.w + adst.w; e3 = e3 > 0.f ? e3 : 0.2f * e3;
      w4 = make_float4(__expf(e0), __expf(e1), __expf(e2), __expf(e3));
    }
    s_sh[wv][lane] = s;
    *(float4*)(&w_sh[wv][lane * 4]) = w4;
    asm volatile("s_waitcnt lgkmcnt(0)" ::: "memory");

    const float* wrow = &w_sh[wv][hd];
    const int*   srow = &s_sh[wv][0];
    int j = 0;
    for (; j + 4 <= nc; j += 4) {
      int sj0 = srow[j], sj1 = srow[j + 1], sj2 = srow[j + 2], sj3 = srow[j + 3];
      float w0 = wrow[4 * j],      w1 = wrow[4 * j + 4];
      float w2 = wrow[4 * j + 8],  w3 = wrow[4 * j + 12];
      uint p0 = *(const uint*)(hbase + ((size_t)((uint)sj0 << 8)));
      uint p1 = *(const uint*)(hbase + ((size_t)((uint)sj1 << 8)));
      uint p2 = *(const uint*)(hbase + ((size_t)((uint)sj2 << 8)));
      uint p3 = *(const uint*)(hbase + ((size_t)((uint)sj3 << 8)));
      f32x2 l0 = __builtin_amdgcn_cvt_pk_f32_fp8(p0, false);
      f32x2 h0 = __builtin_amdgcn_cvt_pk_f32_fp8(p0, true);
      f32x2 l1 = __builtin_amdgcn_cvt_pk_f32_fp8(p1, false);
      f32x2 h1 = __builtin_amdgcn_cvt_pk_f32_fp8(p1, true);
      f32x2 l2 = __builtin_amdgcn_cvt_pk_f32_fp8(p2, false);
      f32x2 h2 = __builtin_amdgcn_cvt_pk_f32_fp8(p2, true);
      f32x2 l3 = __builtin_amdgcn_cvt_pk_f32_fp8(p3, false);
      f32x2 h3 = __builtin_amdgcn_cvt_pk_f32_fp8(p3, true);
      wsum += w0 + w1 + w2 + w3;
      acc.x += w0 * l0.x; acc.y += w0 * l0.y; acc.z += w0 * h0.x; acc.w += w0 * h0.y;
      acc.x += w1 * l1.x; acc.y += w1 * l1.y; acc.z += w1 * h1.x; acc.w += w1 * h1.y;
      acc.x += w2 * l2.x; acc.y += w2 * l2.y; acc.z += w2 * h2.x; acc.w += w2 * h2.y;
      acc.x += w3 * l3.x; acc.y += w3 * l3.y; acc.z += w3 * h3.x; acc.w += w3 * h3.y;
    }
    for (; j < nc; j++) {
      int sj = srow[j];
      float ww = wrow[4 * j];
      uint p = *(const uint*)(hbase + ((size_t)((uint)sj << 8)));
      f32x2 lo = __builtin_amdgcn_cvt_pk_f32_fp8(p, false);
      f32x2 hi = __builtin_amdgcn_cvt_pk_f32_fp8(p, true);
      wsum += ww;
      acc.x += ww * lo.x; acc.y += ww * lo.y;
      acc.z += ww * hi.x; acc.w += ww * hi.y;
    }
  }

  float inv = 1.0f / wsum;  // deg>=1 via self-loop
  float4 v = make_float4(acc.x * inv, acc.y * inv, acc.z * inv, acc.w * inv);

  if (LAYER == 1) {
    const float4 bv = *(const float4*)(bias + lane * 4);
    v.x = fmaxf(v.x + bv.x, 0.f);
    v.y = fmaxf(v.y + bv.y, 0.f);
    v.z = fmaxf(v.z + bv.z, 0.f);
    v.w = fmaxf(v.w + bv.w, 0.f);
    ushort4 h;
    h.x = f2bf(v.x); h.y = f2bf(v.y); h.z = f2bf(v.z); h.w = f2bf(v.w);
    *(ushort4*)(out_h + (size_t)node * 256 + lane * 4) = h;
  } else {
    // fused finale: head-mean + bias + relu + softmax(64)
    v.x += __shfl_xor(v.x, 16); v.y += __shfl_xor(v.y, 16);
    v.z += __shfl_xor(v.z, 16); v.w += __shfl_xor(v.w, 16);
    v.x += __shfl_xor(v.x, 32); v.y += __shfl_xor(v.y, 32);
    v.z += __shfl_xor(v.z, 32); v.w += __shfl_xor(v.w, 32);
    const int c4 = (lane & 15) * 4;
    const float4 bv = *(const float4*)(bias + c4);
    v.x = fmaxf(v.x * 0.25f + bv.x, 0.f);
    v.y = fmaxf(v.y * 0.25f + bv.y, 0.f);
    v.z = fmaxf(v.z * 0.25f + bv.z, 0.f);
    v.w = fmaxf(v.w * 0.25f + bv.w, 0.f);
    float mx = fmaxf(fmaxf(v.x, v.y), fmaxf(v.z, v.w));
    for (int off = 8; off >= 1; off >>= 1) mx = fmaxf(mx, __shfl_xor(mx, off));
    v.x = __expf(v.x - mx); v.y = __expf(v.y - mx);
    v.z = __expf(v.z - mx); v.w = __expf(v.w - mx);
    float sum = v.x + v.y + v.z + v.w;
    for (int off = 8; off >= 1; off >>= 1) sum += __shfl_xor(sum, off);
    float is = 1.0f / sum;
    v.x *= is; v.y *= is; v.z *= is; v.w *= is;
    if (lane < 16) *(float4*)(outp + (size_t)node * 64 + c4) = v;
  }
}

// ---------------------------------------------------------------------------

extern "C" void kernel_launch(void* const* d_in, const int* in_sizes, int n_in,
                              void* d_out, int out_size, void* d_ws, size_t ws_size,
                              hipStream_t stream) {
  const float* x   = (const float*)d_in[0];
  const int*   ei  = (const int*)d_in[1];
  const float* W1  = (const float*)d_in[2];
  const float* as1 = (const float*)d_in[3];
  const float* ad1 = (const float*)d_in[4];
  const float* b1  = (const float*)d_in[5];
  const float* W2  = (const float*)d_in[6];
  const float* as2 = (const float*)d_in[7];
  const float* ad2 = (const float*)d_in[8];
  const float* b2  = (const float*)d_in[9];
  float* out = (float*)d_out;

  const int N = in_sizes[0] / 128;
  const int E = in_sizes[1] / 2;
  const int* srcv = ei;
  const int* dstv = ei + E;

  // ---- workspace layout
  unsigned char* h8 = (unsigned char*)d_ws;       // [N,256] fp8 (both layers)
  ushort* hb   = (ushort*)(h8 + (size_t)N * 256); // [N,256] bf16 (aggr1 out)
  ushort* w1th = hb + (size_t)N * 256;            // [256][128] x2
  ushort* w1tl = w1th + 256 * 128;
  ushort* w2th = w1tl + 256 * 128;                // [256][256] x2
  ushort* w2tl = w2th + 256 * 256;
  float*  zbuf = (float*)(w2tl + 256 * 256);      // a_s1,a_d1,a_s2,a_d2 [16N]
  float* a_s1 = zbuf;
  float* a_d1 = a_s1 + (size_t)N * 4;
  float* a_s2 = a_d1 + (size_t)N * 4;
  float* a_d2 = a_s2 + (size_t)N * 4;
  int* rowptr = (int*)(zbuf + (size_t)N * 16);    // [N+1] (+pad)
  int* cnt    = rowptr + (N + 4);                 // [N]      (memset region)
  int* bflag  = cnt + N;                          // [256]    (memset region)
  int* bsum   = bflag + 256;                      // [256]
  int* pe     = bsum + 256;                       // [E]  per-edge slot
  int* colx   = pe + E;                           // [E]

  const int nb = (N + 255) / 256;  // <=256 required by k_scan lookback
  const int eb = (E + 255) / 256;

  // XCD-aligned swizzled 1-D grid: 16 blocks per group of 8 row blocks
  const int nrb = (N + 127) / 128;
  const int gemm_blocks = ((nrb + 7) / 8) * 16;
  const int wb = (N + 3) / 4;  // one wave per node

  hipMemsetAsync(cnt, 0, ((size_t)N + 256) * 4, stream);  // cnt + bflag
  k_prep_hist<<<384 + eb, 256, 0, stream>>>(W1, W2, w1th, w1tl, w2th, w2tl,
                                            dstv, cnt, pe, E);
  k_scan<<<nb, 256, 0, stream>>>(cnt, rowptr, bsum, bflag, N, E);
  k_gemm1_scatter<<<gemm_blocks + eb, 256, 0, stream>>>(
      x, w1th, w1tl, h8, N, as1, ad1, a_s1, a_d1,
      srcv, dstv, rowptr, pe, colx, E, gemm_blocks);
  k_aggr<1><<<wb, 256, 0, stream>>>(h8, rowptr, colx, a_s1, a_d1, b1,
                                    hb, nullptr, N);
  k_gemm2<<<gemm_blocks, 256, 0, stream>>>(hb, w2th, w2tl, h8, N,
                                           as2, ad2, a_s2, a_d2);
  k_aggr<2><<<wb, 256, 0, stream>>>(h8, rowptr, colx, a_s2, a_d2, b2,
                                    nullptr, out, N);
}

// Round 21
// 292.551 us; speedup vs baseline: 1.5704x; 1.0104x over previous
//
#include <hip/hip_runtime.h>

// ---------------------------------------------------------------------------
// 2-layer GAT (PyG GATConv), MI355X.
// R21 (from R20 = 295.6us best):
//   (1) gemm1's A path: fp32 -> plain bf16 at staging (drop As_l + 3rd MFMA
//       term). x-rounding (0.4%) is upstream of h1's fp8 (3%) -> negligible
//       in quadrature. LDS 20.5->10.2KB, VGPR down, MFMA -33% -> the
//       latency-bound fused gemm1 window gains occupancy (R20: 15% occ,
//       MfmaUtil 6.6%).
//   (2) scatter: 4 edges/thread (1024/block; 3321->831 blocks) for ILP.
//   Everything else frozen from R20.
// ---------------------------------------------------------------------------

typedef __attribute__((ext_vector_type(8))) short short8;
typedef __attribute__((ext_vector_type(4))) float f32x4;
typedef __attribute__((ext_vector_type(2))) float f32x2;

static __device__ __forceinline__ ushort f2bf(float f) {  // RNE
  uint u = __float_as_uint(f);
  return (ushort)((u + 0x7FFFu + ((u >> 16) & 1u)) >> 16);
}
static __device__ __forceinline__ float bf2f(ushort s) {
  return __uint_as_float(((uint)s) << 16);
}
static __device__ __forceinline__ unsigned char f2fp8(float f) {  // e4m3 (HW)
  int p = __builtin_amdgcn_cvt_pk_fp8_f32(f, f, 0, false);
  return (unsigned char)(p & 0xFF);
}
static __device__ __forceinline__ uint4 cvt8bf(const float4& a, const float4& b) {
  uint4 hh;
  hh.x = (uint)f2bf(a.x) | ((uint)f2bf(a.y) << 16);
  hh.y = (uint)f2bf(a.z) | ((uint)f2bf(a.w) << 16);
  hh.z = (uint)f2bf(b.x) | ((uint)f2bf(b.y) << 16);
  hh.w = (uint)f2bf(b.z) | ((uint)f2bf(b.w) << 16);
  return hh;
}

// ---------- fused weight-prep + dst histogram (+ per-edge slot pe) ---------
__global__ __launch_bounds__(256)
void k_prep_hist(const float* __restrict__ W1, const float* __restrict__ W2,
                 ushort* __restrict__ w1th, ushort* __restrict__ w1tl,
                 ushort* __restrict__ w2th, ushort* __restrict__ w2tl,
                 const int* __restrict__ dstv, int* __restrict__ cnt,
                 int* __restrict__ pe, int E) {
  const int b = blockIdx.x;
  if (b < 128) {  // W1 [128][256] -> [256][128] split
    int gid = b * 256 + threadIdx.x;
    int c = gid & 255, k = gid >> 8;
    float w = W1[(size_t)k * 256 + c];
    ushort h = f2bf(w);
    w1th[(size_t)c * 128 + k] = h;
    w1tl[(size_t)c * 128 + k] = f2bf(w - bf2f(h));
  } else if (b < 384) {  // W2 [256][256] -> [256][256] split
    int gid = (b - 128) * 256 + threadIdx.x;
    int c = gid & 255, k = gid >> 8;
    float w = W2[(size_t)k * 256 + c];
    ushort h = f2bf(w);
    w2th[(size_t)c * 256 + k] = h;
    w2tl[(size_t)c * 256 + k] = f2bf(w - bf2f(h));
  } else {  // histogram of dst; atomic return value = edge's slot
    int i = (b - 384) * 256 + threadIdx.x;
    if (i < E) pe[i] = atomicAdd(&cnt[dstv[i]], 1);
  }
}

// Single-pass exclusive scan with decoupled lookback (grid <= 256 blocks).
__global__ __launch_bounds__(256)
void k_scan(const int* __restrict__ cnt, int* __restrict__ rowptr,
            int* __restrict__ bsum, int* __restrict__ bflag, int N, int E) {
  __shared__ int sm[256];
  __shared__ int s_prev;
  const int b = blockIdx.x, tid = threadIdx.x;
  const int gid = b * 256 + tid;
  int v = (gid < N) ? cnt[gid] : 0;
  sm[tid] = v;
  __syncthreads();
  for (int off = 1; off < 256; off <<= 1) {
    int t = (tid >= off) ? sm[tid - off] : 0;
    __syncthreads();
    sm[tid] += t;
    __syncthreads();
  }
  if (tid == 255) {
    atomicExch(&bsum[b], sm[255]);
    __threadfence();
    atomicExch(&bflag[b], 1);
  }
  if (tid == 0) s_prev = 0;
  __syncthreads();
  if (tid < b) {
    while (atomicAdd(&bflag[tid], 0) == 0) {}
    atomicAdd(&s_prev, atomicAdd(&bsum[tid], 0));
  }
  __syncthreads();
  if (gid < N) rowptr[gid] = s_prev + sm[tid] - v;
  if (gid == 0) rowptr[N] = E;
}

// ----------------------------- MFMA GEMM body ------------------------------
// C[N,256] = A_bf16 @ (Bh+Bl)[K,256], Bt stored [256][K]. C -> FP8 e4m3.
// 2 MFMA terms (A*Bh + A*Bl). LDS holds A (bf16) only, 10.2 KB.
// FP32A=1: A is fp32 in global, converted to bf16 during staging.
// FP32A=0: A is already bf16 in global.
// B fragments direct from global (L1/L2-hot panel).
// XCD-aligned swizzle: col-halves of a row block differ by 8 block ids.
template <int FP32A>
static __device__ __forceinline__
void gemm_body(int bid, const void* __restrict__ Aany,
               const ushort* __restrict__ Bth, const ushort* __restrict__ Btl,
               unsigned char* __restrict__ hout, int Nrows, int K,
               const float* __restrict__ att_s, const float* __restrict__ att_d,
               float* __restrict__ a_s, float* __restrict__ a_d) {
  __shared__ ushort As_h[128][40];

  const int nrb = (Nrows + 127) >> 7;
  const int rb = (bid >> 4) * 8 + (bid & 7);
  const int ch = (bid >> 3) & 1;
  if (rb >= nrb) return;
  const int row0 = rb * 128;
  const int col0 = ch * 128;

  const int t = threadIdx.x;
  const int lane = t & 63;
  const int w = t >> 6;
  const int wr = (w >> 1) * 64;
  const int wc = (w & 1) * 64;
  const int lrow = t >> 2;       // 0..63 staging row index
  const int kc = (t & 3) * 8;    // k-chunk within BK=32

  const float*  Af = (const float*)Aany;    // FP32A=1
  const ushort* Ah = (const ushort*)Aany;   // FP32A=0

  f32x4 acc[4][4] = {};

  float4 pf[2][2];
  uint4 pa_h[2];
  const uint4 z4 = make_uint4(0, 0, 0, 0);
#pragma unroll
  for (int p = 0; p < 2; p++) {
    int gr = row0 + p * 64 + lrow;
    if (FP32A) {
      if (gr < Nrows) {
        const float* ap = Af + (size_t)gr * K + kc;
        pf[p][0] = *(const float4*)(ap);
        pf[p][1] = *(const float4*)(ap + 4);
      } else {
        pf[p][0] = make_float4(0.f, 0.f, 0.f, 0.f);
        pf[p][1] = pf[p][0];
      }
    } else {
      if (gr < Nrows) pa_h[p] = *(const uint4*)(Ah + (size_t)gr * K + kc);
      else pa_h[p] = z4;
    }
  }

  const int fr = lane & 15;
  const int fq = lane >> 4;
  const ushort* bb_h = Bth + (size_t)(col0 + wc + fr) * K + fq * 8;
  const ushort* bb_l = Btl + (size_t)(col0 + wc + fr) * K + fq * 8;

  for (int k0 = 0; k0 < K; k0 += 32) {
#pragma unroll
    for (int p = 0; p < 2; p++) {
      uint4 hh;
      if (FP32A) hh = cvt8bf(pf[p][0], pf[p][1]);
      else hh = pa_h[p];
      *(uint4*)(&As_h[p * 64 + lrow][kc]) = hh;
    }
    __syncthreads();

    if (k0 + 32 < K) {
#pragma unroll
      for (int p = 0; p < 2; p++) {
        int gr = row0 + p * 64 + lrow;
        if (FP32A) {
          if (gr < Nrows) {
            const float* ap = Af + (size_t)gr * K + k0 + 32 + kc;
            pf[p][0] = *(const float4*)(ap);
            pf[p][1] = *(const float4*)(ap + 4);
          } else {
            pf[p][0] = make_float4(0.f, 0.f, 0.f, 0.f);
            pf[p][1] = pf[p][0];
          }
        } else {
          if (gr < Nrows)
            pa_h[p] = *(const uint4*)(Ah + (size_t)gr * K + k0 + 32 + kc);
          else pa_h[p] = z4;
        }
      }
    }

    short8 fb_h[4], fb_l[4];
#pragma unroll
    for (int c = 0; c < 4; c++) {
      fb_h[c] = *(const short8*)(bb_h + (size_t)c * 16 * K + k0);
      fb_l[c] = *(const short8*)(bb_l + (size_t)c * 16 * K + k0);
    }
    short8 fa_h[4];
#pragma unroll
    for (int r = 0; r < 4; r++)
      fa_h[r] = *(const short8*)(&As_h[wr + r * 16 + fr][fq * 8]);
#pragma unroll
    for (int r = 0; r < 4; r++)
#pragma unroll
      for (int c = 0; c < 4; c++) {
        acc[r][c] = __builtin_amdgcn_mfma_f32_16x16x32_bf16(fa_h[r], fb_h[c], acc[r][c], 0, 0, 0);
        acc[r][c] = __builtin_amdgcn_mfma_f32_16x16x32_bf16(fa_h[r], fb_l[c], acc[r][c], 0, 0, 0);
      }
    __syncthreads();
  }

  // ---- C write (fp8 e4m3; L2 absorbs the 1B scatter)
#pragma unroll
  for (int r = 0; r < 4; r++)
#pragma unroll
    for (int c = 0; c < 4; c++) {
      int colg = col0 + wc + c * 16 + fr;
#pragma unroll
      for (int reg = 0; reg < 4; reg++) {
        int gr = row0 + wr + r * 16 + fq * 4 + reg;
        if (gr < Nrows)
          hout[(size_t)gr * 256 + colg] = f2fp8(acc[r][c][reg]);
      }
    }

  // ---- attention scores: wave's 64 cols = one head (wc 64-aligned)
  const int head = (col0 + wc) >> 6;
  float asv[4], adv[4];
#pragma unroll
  for (int c = 0; c < 4; c++) {
    asv[c] = att_s[col0 + wc + c * 16 + fr];
    adv[c] = att_d[col0 + wc + c * 16 + fr];
  }
#pragma unroll
  for (int r = 0; r < 4; r++)
#pragma unroll
    for (int reg = 0; reg < 4; reg++) {
      float ps = 0.f, pd = 0.f;
#pragma unroll
      for (int c = 0; c < 4; c++) {
        ps += acc[r][c][reg] * asv[c];
        pd += acc[r][c][reg] * adv[c];
      }
      ps += __shfl_xor(ps, 1); pd += __shfl_xor(pd, 1);
      ps += __shfl_xor(ps, 2); pd += __shfl_xor(pd, 2);
      ps += __shfl_xor(ps, 4); pd += __shfl_xor(pd, 4);
      ps += __shfl_xor(ps, 8); pd += __shfl_xor(pd, 8);
      if (fr == 0) {
        int gr = row0 + wr + r * 16 + fq * 4 + reg;
        if (gr < Nrows) {
          a_s[(size_t)gr * 4 + head] = ps;
          a_d[(size_t)gr * 4 + head] = pd;
        }
      }
    }
}

// ---- fused: gemm1 blocks first, NON-ATOMIC scatter blocks backfill --------
// Scatter: 4 edges/thread (1024/block) for ILP.
__global__ __launch_bounds__(256)
void k_gemm1_scatter(const float* __restrict__ x,
                     const ushort* __restrict__ Bth,
                     const ushort* __restrict__ Btl,
                     unsigned char* __restrict__ hout, int Nrows,
                     const float* __restrict__ att_s,
                     const float* __restrict__ att_d,
                     float* __restrict__ a_s, float* __restrict__ a_d,
                     const int* __restrict__ srcv, const int* __restrict__ dstv,
                     const int* __restrict__ rowptr, const int* __restrict__ pe,
                     int* __restrict__ col, int E, int gemm_blocks) {
  if ((int)blockIdx.x < gemm_blocks) {
    gemm_body<1>(blockIdx.x, x, Bth, Btl, hout, Nrows, 128,
                 att_s, att_d, a_s, a_d);
  } else {
    int base = ((int)blockIdx.x - gemm_blocks) * 1024 + threadIdx.x;
#pragma unroll
    for (int k = 0; k < 4; k++) {
      int i = base + k * 256;
      if (i < E) col[rowptr[dstv[i]] + pe[i]] = srcv[i];
    }
  }
}

__global__ __launch_bounds__(256)
void k_gemm2(const ushort* __restrict__ Ah,
             const ushort* __restrict__ Bth, const ushort* __restrict__ Btl,
             unsigned char* __restrict__ hout, int Nrows,
             const float* __restrict__ att_s, const float* __restrict__ att_d,
             float* __restrict__ a_s, float* __restrict__ a_d) {
  gemm_body<0>(blockIdx.x, Ah, Bth, Btl, hout, Nrows, 256,
               att_s, att_d, a_s, a_d);
}

// ----------------------------- aggregation ---------------------------------
// ONE wave per node; lane owns channels [4*lane, 4*lane+3], head = lane>>4.
// h is FP8 e4m3 for BOTH layers: 4 B/lane gather (256 B/edge), HW cvt decode.
// LAYER 1: relu(acc/den + bias) -> plain bf16.
// LAYER 2: fused finale — head-mean + bias + relu + softmax(64) -> outp.
template <int LAYER>
__global__ __launch_bounds__(256)
void k_aggr(const unsigned char* __restrict__ hsrc,
            const int* __restrict__ rowptr, const int* __restrict__ col,
            const float* __restrict__ a_s, const float* __restrict__ a_d,
            const float* __restrict__ bias,
            ushort* __restrict__ out_h, float* __restrict__ outp, int N) {
  __shared__ int   s_sh[4][64];
  __shared__ float w_sh[4][256];
  const int wv = threadIdx.x >> 6;
  const int lane = threadIdx.x & 63;
  const int node = blockIdx.x * 4 + wv;
  if (node >= N) return;
  const int hd = lane >> 4;
  const int beg = rowptr[node], end = rowptr[node + 1];
  const float4 adst = *(const float4*)(a_d + (size_t)node * 4);

  float4 acc = make_float4(0.f, 0.f, 0.f, 0.f);
  float wsum = 0.f;
  const char* hbase = (const char*)hsrc + lane * 4;  // 256 B row stride

  for (int c0 = beg; c0 < end; c0 += 64) {
    int nc = min(64, end - c0);
    int s = 0;
    float4 w4 = make_float4(0.f, 0.f, 0.f, 0.f);
    if (lane < nc) {
      s = col[c0 + lane];
      float4 a = *(const float4*)(a_s + (size_t)s * 4);
      float e0 = a.x + adst.x; e0 = e0 > 0.f ? e0 : 0.2f * e0;
      float e1 = a.y + adst.y; e1 = e1 > 0.f ? e1 : 0.2f * e1;
      float e2 = a.z + adst.z; e2 = e2 > 0.f ? e2 : 0.2f * e2;
      float e3 = a.w + adst.w; e3 = e3 > 0.f ? e3 : 0.2f * e3;
      w4 = make_float4(__expf(e0), __expf(e1), __expf(e2), __expf(e3));
    }
    s_sh[wv][lane] = s;
    *(float4*)(&w_sh[wv][lane * 4]) = w4;
    asm volatile("s_waitcnt lgkmcnt(0)" ::: "memory");

    const float* wrow = &w_sh[wv][hd];
    const int*   srow = &s_sh[wv][0];
    int j = 0;
    for (; j + 4 <= nc; j += 4) {
      int sj0 = srow[j], sj1 = srow[j + 1], sj2 = srow[j + 2], sj3 = srow[j + 3];
      float w0 = wrow[4 * j],      w1 = wrow[4 * j + 4];
      float w2 = wrow[4 * j + 8],  w3 = wrow[4 * j + 12];
      uint p0 = *(const uint*)(hbase + ((size_t)((uint)sj0 << 8)));
      uint p1 = *(const uint*)(hbase + ((size_t)((uint)sj1 << 8)));
      uint p2 = *(const uint*)(hbase + ((size_t)((uint)sj2 << 8)));
      uint p3 = *(const uint*)(hbase + ((size_t)((uint)sj3 << 8)));
      f32x2 l0 = __builtin_amdgcn_cvt_pk_f32_fp8(p0, false);
      f32x2 h0 = __builtin_amdgcn_cvt_pk_f32_fp8(p0, true);
      f32x2 l1 = __builtin_amdgcn_cvt_pk_f32_fp8(p1, false);
      f32x2 h1 = __builtin_amdgcn_cvt_pk_f32_fp8(p1, true);
      f32x2 l2 = __builtin_amdgcn_cvt_pk_f32_fp8(p2, false);
      f32x2 h2 = __builtin_amdgcn_cvt_pk_f32_fp8(p2, true);
      f32x2 l3 = __builtin_amdgcn_cvt_pk_f32_fp8(p3, false);
      f32x2 h3 = __builtin_amdgcn_cvt_pk_f32_fp8(p3, true);
      wsum += w0 + w1 + w2 + w3;
      acc.x += w0 * l0.x; acc.y += w0 * l0.y; acc.z += w0 * h0.x; acc.w += w0 * h0.y;
      acc.x += w1 * l1.x; acc.y += w1 * l1.y; acc.z += w1 * h1.x; acc.w += w1 * h1.y;
      acc.x += w2 * l2.x; acc.y += w2 * l2.y; acc.z += w2 * h2.x; acc.w += w2 * h2.y;
      acc.x += w3 * l3.x; acc.y += w3 * l3.y; acc.z += w3 * h3.x; acc.w += w3 * h3.y;
    }
    for (; j < nc; j++) {
      int sj = srow[j];
      float ww = wrow[4 * j];
      uint p = *(const uint*)(hbase + ((size_t)((uint)sj << 8)));
      f32x2 lo = __builtin_amdgcn_cvt_pk_f32_fp8(p, false);
      f32x2 hi = __builtin_amdgcn_cvt_pk_f32_fp8(p, true);
      wsum += ww;
      acc.x += ww * lo.x; acc.y += ww * lo.y;
      acc.z += ww * hi.x; acc.w += ww * hi.y;
    }
  }

  float inv = 1.0f / wsum;  // deg>=1 via self-loop
  float4 v = make_float4(acc.x * inv, acc.y * inv, acc.z * inv, acc.w * inv);

  if (LAYER == 1) {
    const float4 bv = *(const float4*)(bias + lane * 4);
    v.x = fmaxf(v.x + bv.x, 0.f);
    v.y = fmaxf(v.y + bv.y, 0.f);
    v.z = fmaxf(v.z + bv.z, 0.f);
    v.w = fmaxf(v.w + bv.w, 0.f);
    ushort4 h;
    h.x = f2bf(v.x); h.y = f2bf(v.y); h.z = f2bf(v.z); h.w = f2bf(v.w);
    *(ushort4*)(out_h + (size_t)node * 256 + lane * 4) = h;
  } else {
    // fused finale: head-mean + bias + relu + softmax(64)
    v.x += __shfl_xor(v.x, 16); v.y += __shfl_xor(v.y, 16);
    v.z += __shfl_xor(v.z, 16); v.w += __shfl_xor(v.w, 16);
    v.x += __shfl_xor(v.x, 32); v.y += __shfl_xor(v.y, 32);
    v.z += __shfl_xor(v.z, 32); v.w += __shfl_xor(v.w, 32);
    const int c4 = (lane & 15) * 4;
    const float4 bv = *(const float4*)(bias + c4);
    v.x = fmaxf(v.x * 0.25f + bv.x, 0.f);
    v.y = fmaxf(v.y * 0.25f + bv.y, 0.f);
    v.z = fmaxf(v.z * 0.25f + bv.z, 0.f);
    v.w = fmaxf(v.w * 0.25f + bv.w, 0.f);
    float mx = fmaxf(fmaxf(v.x, v.y), fmaxf(v.z, v.w));
    for (int off = 8; off >= 1; off >>= 1) mx = fmaxf(mx, __shfl_xor(mx, off));
    v.x = __expf(v.x - mx); v.y = __expf(v.y - mx);
    v.z = __expf(v.z - mx); v.w = __expf(v.w - mx);
    float sum = v.x + v.y + v.z + v.w;
    for (int off = 8; off >= 1; off >>= 1) sum += __shfl_xor(sum, off);
    float is = 1.0f / sum;
    v.x *= is; v.y *= is; v.z *= is; v.w *= is;
    if (lane < 16) *(float4*)(outp + (size_t)node * 64 + c4) = v;
  }
}

// ---------------------------------------------------------------------------

extern "C" void kernel_launch(void* const* d_in, const int* in_sizes, int n_in,
                              void* d_out, int out_size, void* d_ws, size_t ws_size,
                              hipStream_t stream) {
  const float* x   = (const float*)d_in[0];
  const int*   ei  = (const int*)d_in[1];
  const float* W1  = (const float*)d_in[2];
  const float* as1 = (const float*)d_in[3];
  const float* ad1 = (const float*)d_in[4];
  const float* b1  = (const float*)d_in[5];
  const float* W2  = (const float*)d_in[6];
  const float* as2 = (const float*)d_in[7];
  const float* ad2 = (const float*)d_in[8];
  const float* b2  = (const float*)d_in[9];
  float* out = (float*)d_out;

  const int N = in_sizes[0] / 128;
  const int E = in_sizes[1] / 2;
  const int* srcv = ei;
  const int* dstv = ei + E;

  // ---- workspace layout
  unsigned char* h8 = (unsigned char*)d_ws;       // [N,256] fp8 (both layers)
  ushort* hb   = (ushort*)(h8 + (size_t)N * 256); // [N,256] bf16 (aggr1 out)
  ushort* w1th = hb + (size_t)N * 256;            // [256][128] x2
  ushort* w1tl = w1th + 256 * 128;
  ushort* w2th = w1tl + 256 * 128;                // [256][256] x2
  ushort* w2tl = w2th + 256 * 256;
  float*  zbuf = (float*)(w2tl + 256 * 256);      // a_s1,a_d1,a_s2,a_d2 [16N]
  float* a_s1 = zbuf;
  float* a_d1 = a_s1 + (size_t)N * 4;
  float* a_s2 = a_d1 + (size_t)N * 4;
  float* a_d2 = a_s2 + (size_t)N * 4;
  int* rowptr = (int*)(zbuf + (size_t)N * 16);    // [N+1] (+pad)
  int* cnt    = rowptr + (N + 4);                 // [N]      (memset region)
  int* bflag  = cnt + N;                          // [256]    (memset region)
  int* bsum   = bflag + 256;                      // [256]
  int* pe     = bsum + 256;                       // [E]  per-edge slot
  int* colx   = pe + E;                           // [E]

  const int nb = (N + 255) / 256;  // <=256 required by k_scan lookback
  const int eb = (E + 255) / 256;
  const int eb4 = (E + 1023) / 1024;  // 4 edges/thread scatter blocks

  // XCD-aligned swizzled 1-D grid: 16 blocks per group of 8 row blocks
  const int nrb = (N + 127) / 128;
  const int gemm_blocks = ((nrb + 7) / 8) * 16;
  const int wb = (N + 3) / 4;  // one wave per node

  hipMemsetAsync(cnt, 0, ((size_t)N + 256) * 4, stream);  // cnt + bflag
  k_prep_hist<<<384 + eb, 256, 0, stream>>>(W1, W2, w1th, w1tl, w2th, w2tl,
                                            dstv, cnt, pe, E);
  k_scan<<<nb, 256, 0, stream>>>(cnt, rowptr, bsum, bflag, N, E);
  k_gemm1_scatter<<<gemm_blocks + eb4, 256, 0, stream>>>(
      x, w1th, w1tl, h8, N, as1, ad1, a_s1, a_d1,
      srcv, dstv, rowptr, pe, colx, E, gemm_blocks);
  k_aggr<1><<<wb, 256, 0, stream>>>(h8, rowptr, colx, a_s1, a_d1, b1,
                                    hb, nullptr, N);
  k_gemm2<<<gemm_blocks, 256, 0, stream>>>(hb, w2th, w2tl, h8, N,
                                           as2, ad2, a_s2, a_d2);
  k_aggr<2><<<wb, 256, 0, stream>>>(h8, rowptr, colx, a_s2, a_d2, b2,
                                    nullptr, out, N);
}